// Round 1
// baseline (2036.530 us; speedup 1.0000x reference)
//
#include <hip/hip_runtime.h>
#include <math.h>

#define BB 2
#define NN 2048
#define KK 16
#define HH 4
#define CC 8
#define PP 36
#define NEGS 0.2f
#define INVS 0.9999950000374997f  // 1/sqrt(1+1e-5)

// ---------------------------------------------------------------- transposes
__global__ __launch_bounds__(256) void k_transpose(const float* __restrict__ src,
                                                   float* __restrict__ dst,
                                                   int O, int Ctot, int coff, int Cw) {
  int t = blockIdx.x * 256 + threadIdx.x;
  if (t >= O * Cw) return;
  int c = t / O, o = t - c * O;
  dst[t] = src[(size_t)o * Ctot + coff + c];
}

__global__ __launch_bounds__(256) void k_transpose_diff(const float* __restrict__ src,
                                                        float* __restrict__ dst,
                                                        int O, int Cw) {
  int t = blockIdx.x * 256 + threadIdx.x;
  if (t >= O * Cw) return;
  int c = t / O, o = t - c * O;
  dst[t] = src[(size_t)o * 2 * Cw + Cw + c] - src[(size_t)o * 2 * Cw + c];
}

// ---------------------------------------------------------------- ball query
// One wave (64 lanes) per point. Lane l scans indices [l*32, l*32+32); selection
// is "first K in-ball indices in increasing index order", padded with slot 0.
__global__ __launch_bounds__(256) void k_ballquery(const float* __restrict__ pos,
                                                   const int* __restrict__ types,
                                                   int* __restrict__ idxg,
                                                   int* __restrict__ acode,
                                                   float* __restrict__ rel) {
  __shared__ int s_buf[4][KK];
  const float r2 = (float)(0.08 * 0.08);  // match JAX weak-typed python scalar
  int wslot = threadIdx.x >> 6;
  int lane = threadIdx.x & 63;
  int wg = blockIdx.x * 4 + wslot;  // global point id in [0, B*N)
  int b = wg / NN, n = wg - b * NN;
  const float* pb = pos + (size_t)b * NN * 2;
  float px = pb[n * 2 + 0], py = pb[n * 2 + 1];
  float sqn = px * px + py * py;
  unsigned mask = 0u;
  int base = lane * 32;
  for (int j = 0; j < 32; ++j) {
    float qx = pb[(base + j) * 2 + 0], qy = pb[(base + j) * 2 + 1];
    float sqm = qx * qx + qy * qy;
    float d = sqn + sqm - 2.0f * (px * qx + py * qy);
    if (d <= r2) mask |= (1u << j);
  }
  int cnt = __popc(mask);
  int inc = cnt;
#pragma unroll
  for (int off = 1; off < 64; off <<= 1) {
    int v = __shfl_up(inc, off, 64);
    if (lane >= off) inc += v;
  }
  int total = __shfl(inc, 63, 64);
  int excl = inc - cnt;
  unsigned mm = mask;
  int p = excl;
  while (mm && p < KK) {
    int j = __ffs(mm) - 1;
    mm &= mm - 1u;
    s_buf[wslot][p] = base + j;
    ++p;
  }
  __syncthreads();
  int tc = total < KK ? total : KK;
  if (lane < KK) {
    int m0 = s_buf[wslot][0];  // total >= 1 always (self is in-ball)
    int mk = (lane < tc) ? s_buf[wslot][lane] : m0;
    idxg[wg * KK + lane] = mk;
    int core = types[b * NN + n];
    int tg = types[b * NN + mk];
    int s0 = tg < core ? tg : core;
    int s1 = tg < core ? core : tg;
    int code = s0 * CC - (s0 * (s0 - 1)) / 2 + (s1 - s0);
    if (lane == 0 && tg < core) code = PP + core;  // self-coef substitution
    acode[wg * KK + lane] = code;
    rel[(wg * KK + lane) * 2 + 0] = pb[mk * 2 + 0] - px;
    rel[(wg * KK + lane) * 2 + 1] = pb[mk * 2 + 1] - py;
  }
}

// ---------------------------------------------------------------- fused layer
// Block = one point (b,n). Phase 1: stage neighbor rows (+center) or PE in LDS.
// Phase 2: conv (edge-split) -> s_y[K][FOUT]. Phase 3: per-(h,g) attention with
// thread-local K softmax/elu, accumulate over K, write to xc row.
template <int CPREV, int FOUT, bool L1>
__global__ __launch_bounds__(256) void k_layer(
    const float* __restrict__ xprev, int xoff, const float* __restrict__ rel,
    const int* __restrict__ idx, const int* __restrict__ acode,
    const float* __restrict__ wAT, const float* __restrict__ wDT,
    const float* __restrict__ bng, const float* __restrict__ bnb,
    const float* __restrict__ W, const float* __restrict__ ap,
    const float* __restrict__ as_, float* __restrict__ xout, int ooff) {
  __shared__ alignas(16) float s_in[KK][CPREV];
  __shared__ alignas(16) float s_center[CPREV];
  __shared__ alignas(16) float s_y[KK][FOUT];
  __shared__ int s_idx[KK];
  __shared__ int s_ac[KK];
  const int XS = 2048;
  int bn = blockIdx.x;
  int b = bn / NN;
  int tid = threadIdx.x;
  if (tid < KK) {
    s_idx[tid] = idx[bn * KK + tid];
    s_ac[tid] = acode[bn * KK + tid];
  }
  __syncthreads();
  if constexpr (!L1) {
    for (int t = tid; t < CPREV; t += 256)
      s_center[t] = xprev[(size_t)bn * XS + xoff + t];
    for (int t = tid; t < KK * CPREV; t += 256) {
      int k = t / CPREV, c = t - k * CPREV;
      s_in[k][c] = xprev[(size_t)(b * NN + s_idx[k]) * XS + xoff + c];
    }
  } else {
    for (int t = tid; t < KK * 64; t += 256) {
      int k = t >> 6, c = t & 63;
      int coord = c >> 5, j = c & 31;
      int fidx = j & 15;
      float r = rel[(bn * KK + k) * 2 + coord];
      float freq = powf(10000.0f, -(float)fidx * (1.0f / 16.0f));
      float ang = r * freq;
      s_in[k][c] = (j < 16) ? sinf(ang) : cosf(ang);
    }
  }
  __syncthreads();
  // ---- conv: thread owns 4 f-channels x KPT k-slots
  {
    constexpr int FQ = FOUT / 4;
    constexpr int KG = 256 / FQ;
    constexpr int KPT = KK / KG;
    int fq = tid % FQ;
    int kq = tid / FQ;
    int f0 = fq * 4;
    int k0 = kq * KPT;
    float acc[4][KPT];
#pragma unroll
    for (int i = 0; i < 4; ++i)
#pragma unroll
      for (int j = 0; j < KPT; ++j) acc[i][j] = 0.f;
    float accC[4] = {0.f, 0.f, 0.f, 0.f};
    for (int c0 = 0; c0 < CPREV; c0 += 4) {
      float4 sv[KPT];
#pragma unroll
      for (int j = 0; j < KPT; ++j)
        sv[j] = *reinterpret_cast<const float4*>(&s_in[k0 + j][c0]);
      float4 cv4 = {0.f, 0.f, 0.f, 0.f};
      if constexpr (!L1) cv4 = *reinterpret_cast<const float4*>(&s_center[c0]);
#pragma unroll
      for (int ci = 0; ci < 4; ++ci) {
        float4 wa = *reinterpret_cast<const float4*>(&wAT[(c0 + ci) * FOUT + f0]);
#pragma unroll
        for (int j = 0; j < KPT; ++j) {
          float sval = (ci == 0) ? sv[j].x : (ci == 1) ? sv[j].y : (ci == 2) ? sv[j].z : sv[j].w;
          acc[0][j] += wa.x * sval;
          acc[1][j] += wa.y * sval;
          acc[2][j] += wa.z * sval;
          acc[3][j] += wa.w * sval;
        }
        if constexpr (!L1) {
          float4 wd = *reinterpret_cast<const float4*>(&wDT[(c0 + ci) * FOUT + f0]);
          float cval = (ci == 0) ? cv4.x : (ci == 1) ? cv4.y : (ci == 2) ? cv4.z : cv4.w;
          accC[0] += wd.x * cval;
          accC[1] += wd.y * cval;
          accC[2] += wd.z * cval;
          accC[3] += wd.w * cval;
        }
      }
    }
#pragma unroll
    for (int i = 0; i < 4; ++i) {
      float scale = bng[f0 + i] * INVS;
      float bias = bnb[f0 + i];
#pragma unroll
      for (int j = 0; j < KPT; ++j) {
        float v = (acc[i][j] + accC[i]) * scale + bias;
        s_y[k0 + j][f0 + i] = (v >= 0.f) ? v : NEGS * v;
      }
    }
  }
  __syncthreads();
  // ---- attention: thread owns (h, GPT g-columns, all K)
  {
    constexpr int GPT = (FOUT >= 128) ? 2 : 1;
    constexpr int HALF = FOUT / GPT;
    constexpr int SLOTS = HH * HALF;
    constexpr int ROUNDS = SLOTS / 256;
#pragma unroll
    for (int r = 0; r < ROUNDS; ++r) {
      int slot = tid + r * 256;
      int h = slot / HALF;
      int gb = slot - h * HALF;
      float wh[GPT][KK];
#pragma unroll
      for (int gp = 0; gp < GPT; ++gp)
#pragma unroll
        for (int k = 0; k < KK; ++k) wh[gp][k] = 0.f;
      const float* Wh = W + (size_t)h * FOUT * FOUT;
      for (int f0 = 0; f0 < FOUT; f0 += 4) {
        float wv[GPT][4];
#pragma unroll
        for (int gp = 0; gp < GPT; ++gp) {
          int g = gb + gp * HALF;
#pragma unroll
          for (int i = 0; i < 4; ++i) wv[gp][i] = Wh[(size_t)(f0 + i) * FOUT + g];
        }
#pragma unroll
        for (int k = 0; k < KK; ++k) {
          float4 yv = *reinterpret_cast<const float4*>(&s_y[k][f0]);
#pragma unroll
          for (int gp = 0; gp < GPT; ++gp) {
            wh[gp][k] += yv.x * wv[gp][0];
            wh[gp][k] += yv.y * wv[gp][1];
            wh[gp][k] += yv.z * wv[gp][2];
            wh[gp][k] += yv.w * wv[gp][3];
          }
        }
      }
#pragma unroll
      for (int gp = 0; gp < GPT; ++gp) {
        int g = gb + gp * HALF;
        float e[KK];
        float mx = -1e30f;
#pragma unroll
        for (int k = 0; k < KK; ++k) {
          int code = s_ac[k];
          float a = (code < PP) ? ap[((size_t)h * PP + code) * FOUT + g]
                                : as_[((size_t)h * CC + (code - PP)) * FOUT + g];
          float ev = wh[gp][k] * a;
          ev = (ev >= 0.f) ? ev : NEGS * ev;
          e[k] = ev;
          mx = fmaxf(mx, ev);
        }
        float ssum = 0.f;
#pragma unroll
        for (int k = 0; k < KK; ++k) {
          float ex = expf(e[k] - mx);
          e[k] = ex;
          ssum += ex;
        }
        float inv = 1.f / ssum;
        float out = 0.f;
#pragma unroll
        for (int k = 0; k < KK; ++k) {
          float v = e[k] * inv * wh[gp][k];
          out += (v > 0.f) ? v : expm1f(v);
        }
        xout[(size_t)bn * XS + ooff + h * FOUT + g] = out;
      }
    }
  }
}

// ---------------------------------------------------------------- conv5 GEMM
// Y[4096][1024] = leaky(bn(A[4096][2048] @ Bt[2048][1024]))
__global__ __launch_bounds__(256) void k_gemm5(const float* __restrict__ A,
                                               const float* __restrict__ Bt,
                                               const float* __restrict__ g5,
                                               const float* __restrict__ b5,
                                               float* __restrict__ Y) {
  __shared__ alignas(16) float sa[64][36];
  __shared__ alignas(16) float sb[32][64];
  int tid = threadIdx.x;
  int bm = blockIdx.x, bn = blockIdx.y;
  int tr = tid >> 4, tc = tid & 15;
  float acc[4][4];
#pragma unroll
  for (int i = 0; i < 4; ++i)
#pragma unroll
    for (int j = 0; j < 4; ++j) acc[i][j] = 0.f;
  for (int k0 = 0; k0 < 2048; k0 += 32) {
#pragma unroll
    for (int it = 0; it < 8; ++it) {
      int t = tid + it * 256;
      int m = t >> 5, k = t & 31;
      sa[m][k] = A[(size_t)(bm * 64 + m) * 2048 + k0 + k];
    }
#pragma unroll
    for (int it = 0; it < 8; ++it) {
      int t = tid + it * 256;
      int k = t >> 6, n = t & 63;
      sb[k][n] = Bt[(size_t)(k0 + k) * 1024 + bn * 64 + n];
    }
    __syncthreads();
#pragma unroll
    for (int k = 0; k < 32; ++k) {
      float av0 = sa[tr * 4 + 0][k], av1 = sa[tr * 4 + 1][k];
      float av2 = sa[tr * 4 + 2][k], av3 = sa[tr * 4 + 3][k];
      float4 bv = *reinterpret_cast<const float4*>(&sb[k][tc * 4]);
      acc[0][0] += av0 * bv.x; acc[0][1] += av0 * bv.y; acc[0][2] += av0 * bv.z; acc[0][3] += av0 * bv.w;
      acc[1][0] += av1 * bv.x; acc[1][1] += av1 * bv.y; acc[1][2] += av1 * bv.z; acc[1][3] += av1 * bv.w;
      acc[2][0] += av2 * bv.x; acc[2][1] += av2 * bv.y; acc[2][2] += av2 * bv.z; acc[2][3] += av2 * bv.w;
      acc[3][0] += av3 * bv.x; acc[3][1] += av3 * bv.y; acc[3][2] += av3 * bv.z; acc[3][3] += av3 * bv.w;
    }
    __syncthreads();
  }
#pragma unroll
  for (int i = 0; i < 4; ++i) {
    int m = bm * 64 + tr * 4 + i;
#pragma unroll
    for (int j = 0; j < 4; ++j) {
      int o = bn * 64 + tc * 4 + j;
      float v = acc[i][j] * INVS * g5[o] + b5[o];
      Y[(size_t)m * 1024 + o] = (v >= 0.f) ? v : NEGS * v;
    }
  }
}

// ---------------------------------------------------------------- reductions / head
__global__ __launch_bounds__(256) void k_reduce(const float* __restrict__ Y,
                                                float* __restrict__ feat) {
  int t = blockIdx.x * 256 + threadIdx.x;
  if (t >= BB * 1024) return;
  int b = t >> 10, o = t & 1023;
  float mx = -1e30f, sm = 0.f;
  for (int n = 0; n < NN; ++n) {
    float v = Y[(size_t)(b * NN + n) * 1024 + o];
    mx = fmaxf(mx, v);
    sm += v;
  }
  feat[b * 2048 + o] = mx;
  feat[b * 2048 + 1024 + o] = sm * (1.0f / NN);
}

template <bool HASB, bool DOBN, bool ACT>
__global__ __launch_bounds__(256) void k_head(const float* __restrict__ X,
                                              const float* __restrict__ Wm,
                                              const float* __restrict__ bias,
                                              const float* __restrict__ g,
                                              const float* __restrict__ bb,
                                              float* __restrict__ Y, int IN, int ON) {
  int gt = blockIdx.x * 256 + threadIdx.x;
  int w = gt >> 6, lane = gt & 63;
  if (w >= BB * ON) return;
  int b = w / ON, o = w - b * ON;
  const float* x = X + (size_t)b * IN;
  const float* wr = Wm + (size_t)o * IN;
  float s = 0.f;
  for (int c = lane; c < IN; c += 64) s += x[c] * wr[c];
#pragma unroll
  for (int off = 32; off > 0; off >>= 1) s += __shfl_down(s, off, 64);
  if (lane == 0) {
    if (HASB) s += bias[o];
    if (DOBN) s = s * INVS * g[o] + bb[o];
    if (ACT) s = (s >= 0.f) ? s : NEGS * s;
    Y[(size_t)b * ON + o] = s;
  }
}

// ---------------------------------------------------------------- launch
extern "C" void kernel_launch(void* const* d_in, const int* in_sizes, int n_in,
                              void* d_out, int out_size, void* d_ws, size_t ws_size,
                              hipStream_t stream) {
  const float* pos = (const float*)d_in[0];
  const int* types = (const int*)d_in[1];
  const float* conv1_w = (const float*)d_in[2];
  const float* bn1_g = (const float*)d_in[3];
  const float* bn1_b = (const float*)d_in[4];
  const float* W1 = (const float*)d_in[5];
  const float* ap1 = (const float*)d_in[6];
  const float* as1 = (const float*)d_in[7];
  const float* conv2_w = (const float*)d_in[8];
  const float* bn2_g = (const float*)d_in[9];
  const float* bn2_b = (const float*)d_in[10];
  const float* W2 = (const float*)d_in[11];
  const float* ap2 = (const float*)d_in[12];
  const float* as2 = (const float*)d_in[13];
  const float* conv3_w = (const float*)d_in[14];
  const float* bn3_g = (const float*)d_in[15];
  const float* bn3_b = (const float*)d_in[16];
  const float* W3 = (const float*)d_in[17];
  const float* ap3 = (const float*)d_in[18];
  const float* as3 = (const float*)d_in[19];
  const float* conv4_w = (const float*)d_in[20];
  const float* bn4_g = (const float*)d_in[21];
  const float* bn4_b = (const float*)d_in[22];
  const float* W4 = (const float*)d_in[23];
  const float* ap4 = (const float*)d_in[24];
  const float* as4 = (const float*)d_in[25];
  const float* conv5_w = (const float*)d_in[26];
  const float* bn5_g = (const float*)d_in[27];
  const float* bn5_b = (const float*)d_in[28];
  const float* lin1_w = (const float*)d_in[29];
  const float* bn6_g = (const float*)d_in[30];
  const float* bn6_b = (const float*)d_in[31];
  const float* lin2_w = (const float*)d_in[32];
  const float* lin2_b = (const float*)d_in[33];
  const float* bn7_g = (const float*)d_in[34];
  const float* bn7_b = (const float*)d_in[35];
  const float* lin3_w = (const float*)d_in[36];
  const float* lin3_b = (const float*)d_in[37];
  (void)in_sizes; (void)n_in; (void)out_size; (void)ws_size;

  float* ws = (float*)d_ws;
  size_t off = 0;
  auto take = [&](size_t nf) {
    float* p = ws + off;
    off += (nf + 63) & ~(size_t)63;
    return p;
  };
  int* idx = (int*)take(BB * NN * KK);
  int* acode = (int*)take(BB * NN * KK);
  float* rel = take((size_t)BB * NN * KK * 2);
  float* xc = take((size_t)BB * NN * 2048);
  float* y5 = take((size_t)BB * NN * 1024);
  float* feat = take(BB * 2048);
  float* h1 = take(BB * 512);
  float* h2 = take(BB * 256);
  float* w1T = take(64 * 64);
  float* w2AT = take(256 * 64);
  float* w2DT = take(256 * 64);
  float* w3AT = take(256 * 128);
  float* w3DT = take(256 * 128);
  float* w4AT = take(512 * 256);
  float* w4DT = take(512 * 256);
  float* w5T = take((size_t)2048 * 1024);

  dim3 blk(256);
  // weight transposes
  k_transpose<<<dim3((64 * 64 + 255) / 256), blk, 0, stream>>>(conv1_w, w1T, 64, 64, 0, 64);
  k_transpose<<<dim3((256 * 64 + 255) / 256), blk, 0, stream>>>(conv2_w, w2AT, 64, 512, 0, 256);
  k_transpose_diff<<<dim3((256 * 64 + 255) / 256), blk, 0, stream>>>(conv2_w, w2DT, 64, 256);
  k_transpose<<<dim3((256 * 128 + 255) / 256), blk, 0, stream>>>(conv3_w, w3AT, 128, 512, 0, 256);
  k_transpose_diff<<<dim3((256 * 128 + 255) / 256), blk, 0, stream>>>(conv3_w, w3DT, 128, 256);
  k_transpose<<<dim3((512 * 256 + 255) / 256), blk, 0, stream>>>(conv4_w, w4AT, 256, 1024, 0, 512);
  k_transpose_diff<<<dim3((512 * 256 + 255) / 256), blk, 0, stream>>>(conv4_w, w4DT, 256, 512);
  k_transpose<<<dim3((2048 * 1024 + 255) / 256), blk, 0, stream>>>(conv5_w, w5T, 1024, 2048, 0, 2048);

  // ball query + metadata
  k_ballquery<<<dim3(BB * NN / 4), blk, 0, stream>>>(pos, types, idx, acode, rel);

  // fused layers (write into xc columns: x1@0, x2@256, x3@512, x4@1024)
  k_layer<64, 64, true><<<dim3(BB * NN), blk, 0, stream>>>(
      nullptr, 0, rel, idx, acode, w1T, nullptr, bn1_g, bn1_b, W1, ap1, as1, xc, 0);
  k_layer<256, 64, false><<<dim3(BB * NN), blk, 0, stream>>>(
      xc, 0, nullptr, idx, acode, w2AT, w2DT, bn2_g, bn2_b, W2, ap2, as2, xc, 256);
  k_layer<256, 128, false><<<dim3(BB * NN), blk, 0, stream>>>(
      xc, 256, nullptr, idx, acode, w3AT, w3DT, bn3_g, bn3_b, W3, ap3, as3, xc, 512);
  k_layer<512, 256, false><<<dim3(BB * NN), blk, 0, stream>>>(
      xc, 512, nullptr, idx, acode, w4AT, w4DT, bn4_g, bn4_b, W4, ap4, as4, xc, 1024);

  // conv5 + pooling + MLP head
  k_gemm5<<<dim3(64, 16), blk, 0, stream>>>(xc, w5T, bn5_g, bn5_b, y5);
  k_reduce<<<dim3((BB * 1024 + 255) / 256), blk, 0, stream>>>(y5, feat);
  k_head<false, true, true><<<dim3(BB * 512 * 64 / 256), blk, 0, stream>>>(
      feat, lin1_w, nullptr, bn6_g, bn6_b, h1, 2048, 512);
  k_head<true, true, true><<<dim3(BB * 256 * 64 / 256), blk, 0, stream>>>(
      h1, lin2_w, lin2_b, bn7_g, bn7_b, h2, 512, 256);
  k_head<true, false, false><<<dim3(1), blk, 0, stream>>>(
      h2, lin3_w, lin3_b, nullptr, nullptr, (float*)d_out, 256, 2);
}

// Round 2
// 1149.437 us; speedup vs baseline: 1.7718x; 1.7718x over previous
//
#include <hip/hip_runtime.h>
#include <math.h>

#define BB 2
#define NN 2048
#define KK 16
#define HH 4
#define CC 8
#define PP 36
#define NEGS 0.2f
#define INVS 0.9999950000374997f  // 1/sqrt(1+1e-5)

typedef __attribute__((ext_vector_type(8))) short s16x8;
typedef __attribute__((ext_vector_type(8))) unsigned short u16x8;
typedef __attribute__((ext_vector_type(4))) float f32x4;

__device__ inline unsigned short bfh(float x) {
  unsigned u = __float_as_uint(x);
  return (unsigned short)((u + 0x7FFFu + ((u >> 16) & 1u)) >> 16);
}
__device__ inline float bff(unsigned short h) {
  return __uint_as_float(((unsigned)h) << 16);
}
__device__ inline f32x4 mfma16(s16x8 a, s16x8 b, f32x4 c) {
  return __builtin_amdgcn_mfma_f32_16x16x32_bf16(a, b, c, 0, 0, 0);
}

// ---------------------------------------------------------------- ball query
__global__ __launch_bounds__(256) void k_ballquery(const float* __restrict__ pos,
                                                   const int* __restrict__ types,
                                                   int* __restrict__ idxg,
                                                   int* __restrict__ acode,
                                                   float* __restrict__ rel) {
  __shared__ int s_buf[4][KK];
  const float r2 = (float)(0.08 * 0.08);
  int wslot = threadIdx.x >> 6;
  int lane = threadIdx.x & 63;
  int wg = blockIdx.x * 4 + wslot;
  int b = wg / NN, n = wg - b * NN;
  const float* pb = pos + (size_t)b * NN * 2;
  float px = pb[n * 2 + 0], py = pb[n * 2 + 1];
  float sqn = px * px + py * py;
  unsigned mask = 0u;
  int base = lane * 32;
  for (int j = 0; j < 32; ++j) {
    float qx = pb[(base + j) * 2 + 0], qy = pb[(base + j) * 2 + 1];
    float sqm = qx * qx + qy * qy;
    float d = sqn + sqm - 2.0f * (px * qx + py * qy);
    if (d <= r2) mask |= (1u << j);
  }
  int cnt = __popc(mask);
  int inc = cnt;
#pragma unroll
  for (int off = 1; off < 64; off <<= 1) {
    int v = __shfl_up(inc, off, 64);
    if (lane >= off) inc += v;
  }
  int total = __shfl(inc, 63, 64);
  int excl = inc - cnt;
  unsigned mm = mask;
  int p = excl;
  while (mm && p < KK) {
    int j = __ffs(mm) - 1;
    mm &= mm - 1u;
    s_buf[wslot][p] = base + j;
    ++p;
  }
  __syncthreads();
  int tc = total < KK ? total : KK;
  if (lane < KK) {
    int m0 = s_buf[wslot][0];
    int mk = (lane < tc) ? s_buf[wslot][lane] : m0;
    idxg[wg * KK + lane] = mk;
    int core = types[b * NN + n];
    int tg = types[b * NN + mk];
    int s0 = tg < core ? tg : core;
    int s1 = tg < core ? core : tg;
    int code = s0 * CC - (s0 * (s0 - 1)) / 2 + (s1 - s0);
    if (lane == 0 && tg < core) code = PP + core;
    acode[wg * KK + lane] = code;
    rel[(wg * KK + lane) * 2 + 0] = pb[mk * 2 + 0] - px;
    rel[(wg * KK + lane) * 2 + 1] = pb[mk * 2 + 1] - py;
  }
}

// ---------------------------------------------------------------- weight pack
// Produces fragment-major bf16 hi/lo planes for a K x N matrix.
// mode 0: B[k][n] = src[k*srcld + n]             (attn W, srcld=N)
// mode 1: B[k][n] = src[n*srcld + k]             (conv transpose)
//         if Cdiff>0 and k>=Cdiff: minus src[n*srcld + k - Cdiff]
// frag layout: elem(kb,nt,l,i) = B[kb*32 + (l>>4)*8 + i][nt*16 + (l&15)]
// at offset ((nt*KB + kb)*64 + l)*8 + i
__global__ __launch_bounds__(256) void k_pack(const float* __restrict__ src,
                                              unsigned short* __restrict__ dh,
                                              unsigned short* __restrict__ dl,
                                              int KB, int NT, int srcld, int Cdiff,
                                              int mode, int sstride, int dstride) {
  src += (size_t)blockIdx.y * sstride;
  dh += (size_t)blockIdx.y * dstride;
  dl += (size_t)blockIdx.y * dstride;
  int f = blockIdx.x * 256 + threadIdx.x;
  int total = KB * NT * 64;
  if (f >= total) return;
  int l = f & 63;
  int t2 = f >> 6;
  int n = (t2 / KB) * 16 + (l & 15);
  int k0 = (t2 % KB) * 32 + ((l >> 4) * 8);
  size_t o = (size_t)t2 * 512 + (size_t)l * 8;
#pragma unroll
  for (int i = 0; i < 8; ++i) {
    int k = k0 + i;
    float v;
    if (mode == 0) {
      v = src[(size_t)k * srcld + n];
    } else {
      v = src[(size_t)n * srcld + k];
      if (Cdiff > 0 && k >= Cdiff) v -= src[(size_t)n * srcld + k - Cdiff];
    }
    unsigned short hi = bfh(v);
    dh[o + i] = hi;
    dl[o + i] = bfh(v - bff(hi));
  }
}

// ---------------------------------------------------------------- fused layer (MFMA)
// Block = 4 points (64 neighbor-rows). Conv: [64 x K_TOT] @ [K_TOT x FOUT] with
// K-augmentation (channels [CPREV,2*CPREV) = center features, diff-folded weights).
// Attention: per head [64 x FOUT] @ [FOUT x FOUT], softmax over the 16 rows of
// each point-tile done with in-tile shfl_xor reduction. bf16x3 split throughout.
template <int CPREV, int FOUT, bool L1M>
__global__ __launch_bounds__(256) void k_layer_m(
    unsigned short* xh, unsigned short* xl, int xoff,
    const float* __restrict__ rel, const int* __restrict__ idx,
    const int* __restrict__ acode,
    const unsigned short* __restrict__ convh, const unsigned short* __restrict__ convl,
    const unsigned short* __restrict__ attnh, const unsigned short* __restrict__ attnl,
    const float* __restrict__ bng, const float* __restrict__ bnb,
    const float* __restrict__ ap, const float* __restrict__ as_, int ooff) {
  constexpr int K_TOT = L1M ? CPREV : 2 * CPREV;
  constexpr int NCH = K_TOT / 64;
  constexpr int KB = K_TOT / 32;
  constexpr int NT = FOUT / 16;
  constexpr int NT_W = (NT >= 16) ? 4 : ((NT == 8) ? 4 : 2);
  constexpr int MT_W = (NT >= 16) ? 4 : 2;
  constexpr int WCOL = NT / NT_W;
  constexpr int KBA = FOUT / 32;
  constexpr int NPASS = NT / 4;

  __shared__ unsigned short s_xh[64 * 64], s_xl[64 * 64];
  __shared__ unsigned short s_yh[64 * FOUT], s_yl[64 * FOUT];
  __shared__ int s_gsrc[64];
  __shared__ int s_code[64];

  int tid = threadIdx.x;
  int lane = tid & 63;
  int w = tid >> 6;
  int lg = lane >> 4;
  int ln = lane & 15;
  int pgbase = blockIdx.x * 4;

  if (tid < 64) {
    int pg = pgbase + (tid >> 4);
    int b = pg >> 11;
    s_gsrc[tid] = b * 2048 + idx[pg * KK + (tid & 15)];
    s_code[tid] = acode[pg * KK + (tid & 15)];
  }
  __syncthreads();

  // ------------------ conv GEMM over K chunks of 64 ------------------
  int wc = w % WCOL, wr = w / WCOL;
  int mt0 = wr * MT_W, nt0 = wc * NT_W;
  f32x4 cacc[MT_W][NT_W];
#pragma unroll
  for (int m = 0; m < MT_W; ++m)
#pragma unroll
    for (int j = 0; j < NT_W; ++j) cacc[m][j] = (f32x4){0.f, 0.f, 0.f, 0.f};

  for (int ch = 0; ch < NCH; ++ch) {
    // stage chunk into s_x (swizzled)
    {
      int r = tid >> 2, q = tid & 3;
      if constexpr (L1M) {
        int pg = pgbase + (r >> 4);
        float rc = rel[((size_t)pg * KK + (r & 15)) * 2 + (q >> 1)];
        bool isCos = q & 1;
#pragma unroll
        for (int fi = 0; fi < 16; ++fi) {
          float freq = exp2f(-(float)fi * 0.8304820237218406f);  // 10000^(-fi/16)
          float ang = rc * freq;
          float v = isCos ? __cosf(ang) : __sinf(ang);
          unsigned short hi = bfh(v);
          unsigned short lo = bfh(v - bff(hi));
          int by = r * 128 + ((q * 32 + fi * 2) ^ ((r & 7) << 4));
          *(unsigned short*)((char*)s_xh + by) = hi;
          *(unsigned short*)((char*)s_xl + by) = lo;
        }
      } else {
        int c0 = ch * 64;
        bool aug = (c0 >= CPREV);
        int grow = aug ? (pgbase + (r >> 4)) : s_gsrc[r];
        int cc = xoff + (aug ? c0 - CPREV : c0) + q * 16;
        const unsigned short* ph = xh + (size_t)grow * 2048 + cc;
        const unsigned short* pl = xl + (size_t)grow * 2048 + cc;
        u16x8 h0 = *(const u16x8*)(ph);
        u16x8 h1 = *(const u16x8*)(ph + 8);
        u16x8 l0 = *(const u16x8*)(pl);
        u16x8 l1 = *(const u16x8*)(pl + 8);
        int by0 = r * 128 + ((q * 32) ^ ((r & 7) << 4));
        int by1 = r * 128 + ((q * 32 + 16) ^ ((r & 7) << 4));
        *(u16x8*)((char*)s_xh + by0) = h0;
        *(u16x8*)((char*)s_xh + by1) = h1;
        *(u16x8*)((char*)s_xl + by0) = l0;
        *(u16x8*)((char*)s_xl + by1) = l1;
      }
    }
    __syncthreads();
#pragma unroll
    for (int ks = 0; ks < 2; ++ks) {
      s16x8 ah[MT_W], al[MT_W];
#pragma unroll
      for (int m = 0; m < MT_W; ++m) {
        int row = (mt0 + m) * 16 + ln;
        int by = row * 128 + ((ks * 64 + lg * 16) ^ ((row & 7) << 4));
        ah[m] = *(const s16x8*)((const char*)s_xh + by);
        al[m] = *(const s16x8*)((const char*)s_xl + by);
      }
      int kb = ch * 2 + ks;
#pragma unroll
      for (int j = 0; j < NT_W; ++j) {
        size_t fo = ((size_t)(nt0 + j) * KB + kb) * 64 + lane;
        s16x8 bh = ((const s16x8*)convh)[fo];
        s16x8 bl = ((const s16x8*)convl)[fo];
#pragma unroll
        for (int m = 0; m < MT_W; ++m) {
          cacc[m][j] = mfma16(ah[m], bh, cacc[m][j]);
          cacc[m][j] = mfma16(al[m], bh, cacc[m][j]);
          cacc[m][j] = mfma16(ah[m], bl, cacc[m][j]);
        }
      }
    }
    __syncthreads();
  }

  // ------------------ conv epilogue: BN + leaky -> s_y (bf16 h/l, swizzled) ----
#pragma unroll
  for (int j = 0; j < NT_W; ++j) {
    int g = (nt0 + j) * 16 + ln;
    float sc = bng[g] * INVS;
    float bs = bnb[g];
#pragma unroll
    for (int m = 0; m < MT_W; ++m) {
#pragma unroll
      for (int reg = 0; reg < 4; ++reg) {
        int row = (mt0 + m) * 16 + lg * 4 + reg;
        float v = cacc[m][j][reg] * sc + bs;
        v = (v >= 0.f) ? v : NEGS * v;
        unsigned short hi = bfh(v);
        unsigned short lo = bfh(v - bff(hi));
        int by = row * (FOUT * 2) + ((g * 2) ^ ((row & 7) << 4));
        *(unsigned short*)((char*)s_yh + by) = hi;
        *(unsigned short*)((char*)s_yl + by) = lo;
      }
    }
  }
  __syncthreads();

  // ------------------ attention: wave = head ------------------
  {
    int h = w;
    const s16x8* wph = (const s16x8*)(attnh + (size_t)h * FOUT * FOUT);
    const s16x8* wpl = (const s16x8*)(attnl + (size_t)h * FOUT * FOUT);
    const float* aph = ap + (size_t)h * PP * FOUT;
    const float* ash = as_ + (size_t)h * CC * FOUT;
    for (int pass = 0; pass < NPASS; ++pass) {
      f32x4 aacc[4][4];
#pragma unroll
      for (int m = 0; m < 4; ++m)
#pragma unroll
        for (int j = 0; j < 4; ++j) aacc[m][j] = (f32x4){0.f, 0.f, 0.f, 0.f};
      for (int kb = 0; kb < KBA; ++kb) {
        s16x8 ah[4], al[4];
#pragma unroll
        for (int m = 0; m < 4; ++m) {
          int row = m * 16 + ln;
          int by = row * (FOUT * 2) + ((kb * 64 + lg * 16) ^ ((row & 7) << 4));
          ah[m] = *(const s16x8*)((const char*)s_yh + by);
          al[m] = *(const s16x8*)((const char*)s_yl + by);
        }
#pragma unroll
        for (int j = 0; j < 4; ++j) {
          size_t fo = ((size_t)(pass * 4 + j) * KBA + kb) * 64 + lane;
          s16x8 bh = wph[fo];
          s16x8 bl = wpl[fo];
#pragma unroll
          for (int m = 0; m < 4; ++m) {
            aacc[m][j] = mfma16(ah[m], bh, aacc[m][j]);
            aacc[m][j] = mfma16(al[m], bh, aacc[m][j]);
            aacc[m][j] = mfma16(ah[m], bl, aacc[m][j]);
          }
        }
      }
      // epilogue: per point-tile softmax over 16 rows + elu-sum over K
#pragma unroll
      for (int m = 0; m < 4; ++m) {
        int pg = pgbase + m;
#pragma unroll
        for (int j = 0; j < 4; ++j) {
          int g = (pass * 4 + j) * 16 + ln;
          float wv[4], e[4];
          float mx = -3.0e38f;
#pragma unroll
          for (int reg = 0; reg < 4; ++reg) {
            int code = s_code[m * 16 + lg * 4 + reg];
            const float* tb = (code < PP) ? (aph + (size_t)code * FOUT)
                                          : (ash + (size_t)(code - PP) * FOUT);
            float a = tb[g];
            float t = aacc[m][j][reg];
            wv[reg] = t;
            float ev = t * a;
            ev = (ev >= 0.f) ? ev : NEGS * ev;
            e[reg] = ev;
            mx = fmaxf(mx, ev);
          }
          mx = fmaxf(mx, __shfl_xor(mx, 16, 64));
          mx = fmaxf(mx, __shfl_xor(mx, 32, 64));
          float ssum = 0.f;
#pragma unroll
          for (int reg = 0; reg < 4; ++reg) {
            float pe = __expf(e[reg] - mx);
            e[reg] = pe;
            ssum += pe;
          }
          ssum += __shfl_xor(ssum, 16, 64);
          ssum += __shfl_xor(ssum, 32, 64);
          float inv = 1.f / ssum;
          float o = 0.f;
#pragma unroll
          for (int reg = 0; reg < 4; ++reg) {
            float u = e[reg] * inv * wv[reg];
            o += (u > 0.f) ? u : (__expf(u) - 1.f);
          }
          o += __shfl_xor(o, 16, 64);
          o += __shfl_xor(o, 32, 64);
          if (lane < 16) {
            size_t oc = (size_t)pg * 2048 + ooff + h * FOUT + g;
            unsigned short hi = bfh(o);
            xh[oc] = hi;
            xl[oc] = bfh(o - bff(hi));
          }
        }
      }
    }
  }
}

// ---------------------------------------------------------------- conv5 GEMM (MFMA)
// Y5[4096][1024] = leaky(bn(X[4096][2048] @ B[2048][1024])), bf16x3.
__global__ __launch_bounds__(256) void k_gemm5_m(const unsigned short* __restrict__ xh,
                                                 const unsigned short* __restrict__ xl,
                                                 const unsigned short* __restrict__ bph,
                                                 const unsigned short* __restrict__ bpl,
                                                 const float* __restrict__ g5,
                                                 const float* __restrict__ b5,
                                                 float* __restrict__ y5) {
  __shared__ unsigned short s_ah[128 * 64], s_al[128 * 64];
  int tid = threadIdx.x;
  int lane = tid & 63;
  int w = tid >> 6;
  int lg = lane >> 4;
  int ln = lane & 15;
  int bm = blockIdx.x, bn = blockIdx.y;
  int wm = w >> 1, wn = w & 1;
  f32x4 acc[4][4];
#pragma unroll
  for (int m = 0; m < 4; ++m)
#pragma unroll
    for (int j = 0; j < 4; ++j) acc[m][j] = (f32x4){0.f, 0.f, 0.f, 0.f};

  for (int ch = 0; ch < 32; ++ch) {
    {
      int r = tid >> 1, cq = (tid & 1) * 32;
      size_t base = (size_t)(bm * 128 + r) * 2048 + ch * 64 + cq;
#pragma unroll
      for (int ii = 0; ii < 4; ++ii) {
        u16x8 hv = *(const u16x8*)(xh + base + ii * 8);
        u16x8 lv = *(const u16x8*)(xl + base + ii * 8);
        int by = r * 128 + ((cq * 2 + ii * 16) ^ ((r & 7) << 4));
        *(u16x8*)((char*)s_ah + by) = hv;
        *(u16x8*)((char*)s_al + by) = lv;
      }
    }
    __syncthreads();
#pragma unroll
    for (int ks = 0; ks < 2; ++ks) {
      s16x8 ah[4], al[4];
#pragma unroll
      for (int m = 0; m < 4; ++m) {
        int row = wm * 64 + m * 16 + ln;
        int by = row * 128 + ((ks * 64 + lg * 16) ^ ((row & 7) << 4));
        ah[m] = *(const s16x8*)((const char*)s_ah + by);
        al[m] = *(const s16x8*)((const char*)s_al + by);
      }
      int kb = ch * 2 + ks;
#pragma unroll
      for (int j = 0; j < 4; ++j) {
        size_t fo = ((size_t)(bn * 8 + wn * 4 + j) * 64 + kb) * 64 + lane;
        s16x8 bh = ((const s16x8*)bph)[fo];
        s16x8 bl = ((const s16x8*)bpl)[fo];
#pragma unroll
        for (int m = 0; m < 4; ++m) {
          acc[m][j] = mfma16(ah[m], bh, acc[m][j]);
          acc[m][j] = mfma16(al[m], bh, acc[m][j]);
          acc[m][j] = mfma16(ah[m], bl, acc[m][j]);
        }
      }
    }
    __syncthreads();
  }
#pragma unroll
  for (int j = 0; j < 4; ++j) {
    int g = bn * 128 + wn * 64 + j * 16 + ln;
    float sc = g5[g] * INVS;
    float bs = b5[g];
#pragma unroll
    for (int m = 0; m < 4; ++m) {
#pragma unroll
      for (int reg = 0; reg < 4; ++reg) {
        int row = bm * 128 + wm * 64 + m * 16 + lg * 4 + reg;
        float v = acc[m][j][reg] * sc + bs;
        y5[(size_t)row * 1024 + g] = (v >= 0.f) ? v : NEGS * v;
      }
    }
  }
}

// ---------------------------------------------------------------- reductions / head
__global__ __launch_bounds__(256) void k_reduce(const float* __restrict__ Y,
                                                float* __restrict__ feat) {
  int t = blockIdx.x * 256 + threadIdx.x;
  if (t >= BB * 1024) return;
  int b = t >> 10, o = t & 1023;
  float mx = -1e30f, sm = 0.f;
  for (int n = 0; n < NN; ++n) {
    float v = Y[(size_t)(b * NN + n) * 1024 + o];
    mx = fmaxf(mx, v);
    sm += v;
  }
  feat[b * 2048 + o] = mx;
  feat[b * 2048 + 1024 + o] = sm * (1.0f / NN);
}

template <bool HASB, bool DOBN, bool ACT>
__global__ __launch_bounds__(256) void k_head(const float* __restrict__ X,
                                              const float* __restrict__ Wm,
                                              const float* __restrict__ bias,
                                              const float* __restrict__ g,
                                              const float* __restrict__ bb,
                                              float* __restrict__ Y, int IN, int ON) {
  int gt = blockIdx.x * 256 + threadIdx.x;
  int w = gt >> 6, lane = gt & 63;
  if (w >= BB * ON) return;
  int b = w / ON, o = w - b * ON;
  const float* x = X + (size_t)b * IN;
  const float* wr = Wm + (size_t)o * IN;
  float s = 0.f;
  for (int c = lane; c < IN; c += 64) s += x[c] * wr[c];
#pragma unroll
  for (int off = 32; off > 0; off >>= 1) s += __shfl_down(s, off, 64);
  if (lane == 0) {
    if (HASB) s += bias[o];
    if (DOBN) s = s * INVS * g[o] + bb[o];
    if (ACT) s = (s >= 0.f) ? s : NEGS * s;
    Y[(size_t)b * ON + o] = s;
  }
}

// ---------------------------------------------------------------- launch
extern "C" void kernel_launch(void* const* d_in, const int* in_sizes, int n_in,
                              void* d_out, int out_size, void* d_ws, size_t ws_size,
                              hipStream_t stream) {
  const float* pos = (const float*)d_in[0];
  const int* types = (const int*)d_in[1];
  const float* conv1_w = (const float*)d_in[2];
  const float* bn1_g = (const float*)d_in[3];
  const float* bn1_b = (const float*)d_in[4];
  const float* W1 = (const float*)d_in[5];
  const float* ap1 = (const float*)d_in[6];
  const float* as1 = (const float*)d_in[7];
  const float* conv2_w = (const float*)d_in[8];
  const float* bn2_g = (const float*)d_in[9];
  const float* bn2_b = (const float*)d_in[10];
  const float* W2 = (const float*)d_in[11];
  const float* ap2 = (const float*)d_in[12];
  const float* as2 = (const float*)d_in[13];
  const float* conv3_w = (const float*)d_in[14];
  const float* bn3_g = (const float*)d_in[15];
  const float* bn3_b = (const float*)d_in[16];
  const float* W3 = (const float*)d_in[17];
  const float* ap3 = (const float*)d_in[18];
  const float* as3 = (const float*)d_in[19];
  const float* conv4_w = (const float*)d_in[20];
  const float* bn4_g = (const float*)d_in[21];
  const float* bn4_b = (const float*)d_in[22];
  const float* W4 = (const float*)d_in[23];
  const float* ap4 = (const float*)d_in[24];
  const float* as4 = (const float*)d_in[25];
  const float* conv5_w = (const float*)d_in[26];
  const float* bn5_g = (const float*)d_in[27];
  const float* bn5_b = (const float*)d_in[28];
  const float* lin1_w = (const float*)d_in[29];
  const float* bn6_g = (const float*)d_in[30];
  const float* bn6_b = (const float*)d_in[31];
  const float* lin2_w = (const float*)d_in[32];
  const float* lin2_b = (const float*)d_in[33];
  const float* bn7_g = (const float*)d_in[34];
  const float* bn7_b = (const float*)d_in[35];
  const float* lin3_w = (const float*)d_in[36];
  const float* lin3_b = (const float*)d_in[37];
  (void)in_sizes; (void)n_in; (void)out_size; (void)ws_size;

  float* ws = (float*)d_ws;
  size_t off = 0;
  auto take = [&](size_t nf) {
    float* p = ws + off;
    off += (nf + 63) & ~(size_t)63;
    return p;
  };
  auto takeu = [&](size_t nu) { return (unsigned short*)take((nu + 1) / 2); };

  int* idx = (int*)take(BB * NN * KK);
  int* acode = (int*)take(BB * NN * KK);
  float* rel = take((size_t)BB * NN * KK * 2);
  unsigned short* xh = takeu((size_t)BB * NN * 2048);
  unsigned short* xl = takeu((size_t)BB * NN * 2048);
  float* y5 = take((size_t)BB * NN * 1024);
  float* feat = take(BB * 2048);
  float* h1 = take(BB * 512);
  float* h2 = take(BB * 256);
  unsigned short* c1h = takeu(64 * 64);
  unsigned short* c1l = takeu(64 * 64);
  unsigned short* c2h = takeu(512 * 64);
  unsigned short* c2l = takeu(512 * 64);
  unsigned short* c3h = takeu(512 * 128);
  unsigned short* c3l = takeu(512 * 128);
  unsigned short* c4h = takeu(1024 * 256);
  unsigned short* c4l = takeu(1024 * 256);
  unsigned short* a1h = takeu(4 * 64 * 64);
  unsigned short* a1l = takeu(4 * 64 * 64);
  unsigned short* a2h = takeu(4 * 64 * 64);
  unsigned short* a2l = takeu(4 * 64 * 64);
  unsigned short* a3h = takeu(4 * 128 * 128);
  unsigned short* a3l = takeu(4 * 128 * 128);
  unsigned short* a4h = takeu(4 * 256 * 256);
  unsigned short* a4l = takeu(4 * 256 * 256);
  unsigned short* g5h = takeu((size_t)2048 * 1024);
  unsigned short* g5l = takeu((size_t)2048 * 1024);

  dim3 blk(256);
  // weight packing (fragment-major bf16 hi/lo)
  k_pack<<<dim3(2, 1), blk, 0, stream>>>(conv1_w, c1h, c1l, 2, 4, 64, 0, 1, 0, 0);
  k_pack<<<dim3(16, 1), blk, 0, stream>>>(conv2_w, c2h, c2l, 16, 4, 512, 256, 1, 0, 0);
  k_pack<<<dim3(32, 1), blk, 0, stream>>>(conv3_w, c3h, c3l, 16, 8, 512, 256, 1, 0, 0);
  k_pack<<<dim3(128, 1), blk, 0, stream>>>(conv4_w, c4h, c4l, 32, 16, 1024, 512, 1, 0, 0);
  k_pack<<<dim3(2, 4), blk, 0, stream>>>(W1, a1h, a1l, 2, 4, 64, 0, 0, 64 * 64, 64 * 64);
  k_pack<<<dim3(2, 4), blk, 0, stream>>>(W2, a2h, a2l, 2, 4, 64, 0, 0, 64 * 64, 64 * 64);
  k_pack<<<dim3(8, 4), blk, 0, stream>>>(W3, a3h, a3l, 4, 8, 128, 0, 0, 128 * 128, 128 * 128);
  k_pack<<<dim3(32, 4), blk, 0, stream>>>(W4, a4h, a4l, 8, 16, 256, 0, 0, 256 * 256, 256 * 256);
  k_pack<<<dim3(1024, 1), blk, 0, stream>>>(conv5_w, g5h, g5l, 64, 64, 2048, 0, 1, 0, 0);

  // ball query + metadata
  k_ballquery<<<dim3(BB * NN / 4), blk, 0, stream>>>(pos, types, idx, acode, rel);

  // fused layers (outputs into bf16 h/l planes: x1@0, x2@256, x3@512, x4@1024)
  k_layer_m<64, 64, true><<<dim3(BB * NN / 4), blk, 0, stream>>>(
      xh, xl, 0, rel, idx, acode, c1h, c1l, a1h, a1l, bn1_g, bn1_b, ap1, as1, 0);
  k_layer_m<256, 64, false><<<dim3(BB * NN / 4), blk, 0, stream>>>(
      xh, xl, 0, rel, idx, acode, c2h, c2l, a2h, a2l, bn2_g, bn2_b, ap2, as2, 256);
  k_layer_m<256, 128, false><<<dim3(BB * NN / 4), blk, 0, stream>>>(
      xh, xl, 256, rel, idx, acode, c3h, c3l, a3h, a3l, bn3_g, bn3_b, ap3, as3, 512);
  k_layer_m<512, 256, false><<<dim3(BB * NN / 4), blk, 0, stream>>>(
      xh, xl, 512, rel, idx, acode, c4h, c4l, a4h, a4l, bn4_g, bn4_b, ap4, as4, 1024);

  // conv5 + pooling + MLP head
  k_gemm5_m<<<dim3(32, 8), blk, 0, stream>>>(xh, xl, g5h, g5l, bn5_g, bn5_b, y5);
  k_reduce<<<dim3((BB * 1024 + 255) / 256), blk, 0, stream>>>(y5, feat);
  k_head<false, true, true><<<dim3(BB * 512 * 64 / 256), blk, 0, stream>>>(
      feat, lin1_w, nullptr, bn6_g, bn6_b, h1, 2048, 512);
  k_head<true, true, true><<<dim3(BB * 256 * 64 / 256), blk, 0, stream>>>(
      h1, lin2_w, lin2_b, bn7_g, bn7_b, h2, 512, 256);
  k_head<true, false, false><<<dim3(1), blk, 0, stream>>>(
      h2, lin3_w, lin3_b, nullptr, nullptr, (float*)d_out, 256, 2);
}

// Round 3
// 915.100 us; speedup vs baseline: 2.2255x; 1.2561x over previous
//
#include <hip/hip_runtime.h>
#include <math.h>

#define BB 2
#define NN 2048
#define KK 16
#define HH 4
#define CC 8
#define PP 36
#define NEGS 0.2f
#define INVS 0.9999950000374997f  // 1/sqrt(1+1e-5)

typedef __attribute__((ext_vector_type(8))) short s16x8;
typedef __attribute__((ext_vector_type(8))) unsigned short u16x8;
typedef __attribute__((ext_vector_type(4))) float f32x4;

__device__ inline unsigned short bfh(float x) {
  unsigned u = __float_as_uint(x);
  return (unsigned short)((u + 0x7FFFu + ((u >> 16) & 1u)) >> 16);
}
__device__ inline float bff(unsigned short h) {
  return __uint_as_float(((unsigned)h) << 16);
}
__device__ inline f32x4 mfma16(s16x8 a, s16x8 b, f32x4 c) {
  return __builtin_amdgcn_mfma_f32_16x16x32_bf16(a, b, c, 0, 0, 0);
}

// ---------------------------------------------------------------- ball query
__global__ __launch_bounds__(256) void k_ballquery(const float* __restrict__ pos,
                                                   const int* __restrict__ types,
                                                   int* __restrict__ idxg,
                                                   int* __restrict__ acode,
                                                   float* __restrict__ rel) {
  __shared__ int s_buf[4][KK];
  const float r2 = (float)(0.08 * 0.08);
  int wslot = threadIdx.x >> 6;
  int lane = threadIdx.x & 63;
  int wg = blockIdx.x * 4 + wslot;
  int b = wg / NN, n = wg - b * NN;
  const float* pb = pos + (size_t)b * NN * 2;
  float px = pb[n * 2 + 0], py = pb[n * 2 + 1];
  float sqn = px * px + py * py;
  unsigned mask = 0u;
  int base = lane * 32;
  for (int j = 0; j < 32; ++j) {
    float qx = pb[(base + j) * 2 + 0], qy = pb[(base + j) * 2 + 1];
    float sqm = qx * qx + qy * qy;
    float d = sqn + sqm - 2.0f * (px * qx + py * qy);
    if (d <= r2) mask |= (1u << j);
  }
  int cnt = __popc(mask);
  int inc = cnt;
#pragma unroll
  for (int off = 1; off < 64; off <<= 1) {
    int v = __shfl_up(inc, off, 64);
    if (lane >= off) inc += v;
  }
  int total = __shfl(inc, 63, 64);
  int excl = inc - cnt;
  unsigned mm = mask;
  int p = excl;
  while (mm && p < KK) {
    int j = __ffs(mm) - 1;
    mm &= mm - 1u;
    s_buf[wslot][p] = base + j;
    ++p;
  }
  __syncthreads();
  int tc = total < KK ? total : KK;
  if (lane < KK) {
    int m0 = s_buf[wslot][0];
    int mk = (lane < tc) ? s_buf[wslot][lane] : m0;
    idxg[wg * KK + lane] = mk;
    int core = types[b * NN + n];
    int tg = types[b * NN + mk];
    int s0 = tg < core ? tg : core;
    int s1 = tg < core ? core : tg;
    int code = s0 * CC - (s0 * (s0 - 1)) / 2 + (s1 - s0);
    if (lane == 0 && tg < core) code = PP + core;
    acode[wg * KK + lane] = code;
    rel[(wg * KK + lane) * 2 + 0] = pb[mk * 2 + 0] - px;
    rel[(wg * KK + lane) * 2 + 1] = pb[mk * 2 + 1] - py;
  }
}

// ---------------------------------------------------------------- weight pack
// frag layout: elem(kb,nt,l,i) = B[kb*32 + (l>>4)*8 + i][nt*16 + (l&15)]
__global__ __launch_bounds__(256) void k_pack(const float* __restrict__ src,
                                              unsigned short* __restrict__ dh,
                                              unsigned short* __restrict__ dl,
                                              int KB, int NT, int srcld, int Cdiff,
                                              int mode, int sstride, int dstride) {
  src += (size_t)blockIdx.y * sstride;
  dh += (size_t)blockIdx.y * dstride;
  dl += (size_t)blockIdx.y * dstride;
  int f = blockIdx.x * 256 + threadIdx.x;
  int total = KB * NT * 64;
  if (f >= total) return;
  int l = f & 63;
  int t2 = f >> 6;
  int n = (t2 / KB) * 16 + (l & 15);
  int k0 = (t2 % KB) * 32 + ((l >> 4) * 8);
  size_t o = (size_t)t2 * 512 + (size_t)l * 8;
#pragma unroll
  for (int i = 0; i < 8; ++i) {
    int k = k0 + i;
    float v;
    if (mode == 0) {
      v = src[(size_t)k * srcld + n];
    } else {
      v = src[(size_t)n * srcld + k];
      if (Cdiff > 0 && k >= Cdiff) v -= src[(size_t)n * srcld + k - Cdiff];
    }
    unsigned short hi = bfh(v);
    dh[o + i] = hi;
    dl[o + i] = bfh(v - bff(hi));
  }
}

// ---------------------------------------------------------------- fused layer (MFMA, 8 waves)
// Block = 4 points (64 neighbor rows), 512 threads.
// Conv: [64 x K_TOT] @ [K_TOT x FOUT], reg-staged pipeline (T14), x/y LDS union.
// Attention: wave = (head, N-half); per-tile softmax via shfl_xor.
template <int CPREV, int FOUT, bool L1M>
__global__ __launch_bounds__(512, 3) void k_layer_m(
    unsigned short* xh, unsigned short* xl, int xoff,
    const float* __restrict__ rel, const int* __restrict__ idx,
    const int* __restrict__ acode,
    const unsigned short* __restrict__ convh, const unsigned short* __restrict__ convl,
    const unsigned short* __restrict__ attnh, const unsigned short* __restrict__ attnl,
    const float* __restrict__ bng, const float* __restrict__ bnb,
    const float* __restrict__ ap, const float* __restrict__ as_, int ooff) {
  constexpr int K_TOT = L1M ? CPREV : 2 * CPREV;
  constexpr int NCH = K_TOT / 64;
  constexpr int KB = K_TOT / 32;
  constexpr int NT = FOUT / 16;
  constexpr int NT_W = NT / 4;          // conv n-tiles per wave (2x4 wave grid)
  constexpr int NTW_A = NT / 2;         // attn n-tiles per wave (head x half)
  constexpr int JW = (NTW_A > 4) ? 4 : NTW_A;
  constexpr int NPASS = NTW_A / JW;
  constexpr int KBA = FOUT / 32;
  constexpr int YH_BYTES = 64 * FOUT * 2;  // one y plane
  constexpr int S_BYTES = (2 * YH_BYTES > 16384) ? 2 * YH_BYTES : 16384;

  __shared__ alignas(16) char s_mem[S_BYTES];  // union: x-stage (16KB) / y (hi|lo)
  __shared__ int s_gsrc[64];
  __shared__ int s_code[64];

  int tid = threadIdx.x;
  int lane = tid & 63;
  int w = tid >> 6;
  int lg = lane >> 4;
  int ln = lane & 15;
  int pgbase = blockIdx.x * 4;

  if (tid < 64) {
    int pg = pgbase + (tid >> 4);
    int b = pg >> 11;
    s_gsrc[tid] = b * 2048 + idx[pg * KK + (tid & 15)];
    s_code[tid] = acode[pg * KK + (tid & 15)];
  }
  __syncthreads();

  // staging geometry: thread -> (row sr, 8-channel group sq)
  int sr = tid >> 3;
  int sq = tid & 7;
  int wbyH = sr * 128 + ((sq * 16) ^ ((sr & 7) << 4));

  // conv wave roles: 2 row-halves x 4 col-quarters
  int wr = w >> 2, wc = w & 3;
  f32x4 cacc[2][NT_W];
#pragma unroll
  for (int m = 0; m < 2; ++m)
#pragma unroll
    for (int j = 0; j < NT_W; ++j) cacc[m][j] = (f32x4){0.f, 0.f, 0.f, 0.f};

  auto compute_chunk = [&](int ch) {
#pragma unroll
    for (int ks = 0; ks < 2; ++ks) {
      s16x8 ah[2], al[2];
#pragma unroll
      for (int m = 0; m < 2; ++m) {
        int row = wr * 32 + m * 16 + ln;
        int by = row * 128 + ((ks * 64 + lg * 16) ^ ((row & 7) << 4));
        ah[m] = *(const s16x8*)(s_mem + by);
        al[m] = *(const s16x8*)(s_mem + 8192 + by);
      }
      int kb = ch * 2 + ks;
#pragma unroll
      for (int j = 0; j < NT_W; ++j) {
        size_t fo = ((size_t)(wc * NT_W + j) * KB + kb) * 64 + lane;
        s16x8 bh = ((const s16x8*)convh)[fo];
        s16x8 bl = ((const s16x8*)convl)[fo];
#pragma unroll
        for (int m = 0; m < 2; ++m) {
          cacc[m][j] = mfma16(ah[m], bh, cacc[m][j]);
          cacc[m][j] = mfma16(al[m], bh, cacc[m][j]);
          cacc[m][j] = mfma16(ah[m], bl, cacc[m][j]);
        }
      }
    }
  };

  if constexpr (L1M) {
    // compute PE in-place, single chunk
    int pg = pgbase + (sr >> 4);
    float rc = rel[((size_t)pg * KK + (sr & 15)) * 2 + (sq >> 2)];
    bool isSin = (sq & 3) < 2;
    unsigned short hb[8], lb[8];
#pragma unroll
    for (int i = 0; i < 8; ++i) {
      int j = (sq & 3) * 8 + i;
      int fidx = j & 15;
      float freq = exp2f(-(float)fidx * 0.8304820237218406f);  // 10000^(-fidx/16)
      float ang = rc * freq;
      float v = isSin ? __sinf(ang) : __cosf(ang);
      unsigned short hi = bfh(v);
      hb[i] = hi;
      lb[i] = bfh(v - bff(hi));
    }
    *(u16x8*)(s_mem + wbyH) = *(u16x8*)hb;
    *(u16x8*)(s_mem + 8192 + wbyH) = *(u16x8*)lb;
    __syncthreads();
    compute_chunk(0);
    __syncthreads();
  } else {
    const unsigned short* gAh = xh + (size_t)s_gsrc[sr] * 2048 + xoff + sq * 8;
    const unsigned short* gAl = xl + (size_t)s_gsrc[sr] * 2048 + xoff + sq * 8;
    const unsigned short* gCh = xh + (size_t)(pgbase + (sr >> 4)) * 2048 + xoff + sq * 8;
    const unsigned short* gCl = xl + (size_t)(pgbase + (sr >> 4)) * 2048 + xoff + sq * 8;
    auto srcp = [&](int ch, int plane) -> const unsigned short* {
      int c0 = ch * 64;
      bool aug = c0 >= CPREV;
      int coff = aug ? c0 - CPREV : c0;
      const unsigned short* p = plane ? (aug ? gCl : gAl) : (aug ? gCh : gAh);
      return p + coff;
    };
    u16x8 hv = *(const u16x8*)srcp(0, 0);
    u16x8 lv = *(const u16x8*)srcp(0, 1);
    for (int ch = 0; ch < NCH; ++ch) {
      *(u16x8*)(s_mem + wbyH) = hv;
      *(u16x8*)(s_mem + 8192 + wbyH) = lv;
      __syncthreads();
      if (ch + 1 < NCH) {  // async prefetch: loads overlap this chunk's MFMA
        hv = *(const u16x8*)srcp(ch + 1, 0);
        lv = *(const u16x8*)srcp(ch + 1, 1);
      }
      compute_chunk(ch);
      __syncthreads();
    }
  }

  // conv epilogue: BN + leaky -> y (overlays x buffer; conv loop ended w/ barrier)
#pragma unroll
  for (int j = 0; j < NT_W; ++j) {
    int g = (wc * NT_W + j) * 16 + ln;
    float sc = bng[g] * INVS;
    float bs = bnb[g];
#pragma unroll
    for (int m = 0; m < 2; ++m) {
#pragma unroll
      for (int reg = 0; reg < 4; ++reg) {
        int row = wr * 32 + m * 16 + lg * 4 + reg;
        float v = cacc[m][j][reg] * sc + bs;
        v = (v >= 0.f) ? v : NEGS * v;
        unsigned short hi = bfh(v);
        unsigned short lo = bfh(v - bff(hi));
        int by = row * (FOUT * 2) + ((g * 2) ^ ((row & 7) << 4));
        *(unsigned short*)(s_mem + by) = hi;
        *(unsigned short*)(s_mem + YH_BYTES + by) = lo;
      }
    }
  }
  __syncthreads();

  // attention: wave = (head h, N-half nh)
  {
    int h = w >> 1, nh = w & 1;
    const s16x8* wph = (const s16x8*)(attnh + (size_t)h * FOUT * FOUT);
    const s16x8* wpl = (const s16x8*)(attnl + (size_t)h * FOUT * FOUT);
    const float* aph = ap + (size_t)h * PP * FOUT;
    const float* ash = as_ + (size_t)h * CC * FOUT;
    for (int pass = 0; pass < NPASS; ++pass) {
      f32x4 aacc[4][JW];
#pragma unroll
      for (int m = 0; m < 4; ++m)
#pragma unroll
        for (int j = 0; j < JW; ++j) aacc[m][j] = (f32x4){0.f, 0.f, 0.f, 0.f};
      for (int kb = 0; kb < KBA; ++kb) {
        s16x8 ah[4], al[4];
#pragma unroll
        for (int m = 0; m < 4; ++m) {
          int row = m * 16 + ln;
          int by = row * (FOUT * 2) + ((kb * 64 + lg * 16) ^ ((row & 7) << 4));
          ah[m] = *(const s16x8*)(s_mem + by);
          al[m] = *(const s16x8*)(s_mem + YH_BYTES + by);
        }
#pragma unroll
        for (int j = 0; j < JW; ++j) {
          int nt = nh * NTW_A + pass * JW + j;
          size_t fo = ((size_t)nt * KBA + kb) * 64 + lane;
          s16x8 bh = wph[fo];
          s16x8 bl = wpl[fo];
#pragma unroll
          for (int m = 0; m < 4; ++m) {
            aacc[m][j] = mfma16(ah[m], bh, aacc[m][j]);
            aacc[m][j] = mfma16(al[m], bh, aacc[m][j]);
            aacc[m][j] = mfma16(ah[m], bl, aacc[m][j]);
          }
        }
      }
#pragma unroll
      for (int m = 0; m < 4; ++m) {
        int pg = pgbase + m;
#pragma unroll
        for (int j = 0; j < JW; ++j) {
          int nt = nh * NTW_A + pass * JW + j;
          int g = nt * 16 + ln;
          float wv[4], e[4];
          float mx = -3.0e38f;
#pragma unroll
          for (int reg = 0; reg < 4; ++reg) {
            int code = s_code[m * 16 + lg * 4 + reg];
            const float* tb = (code < PP) ? (aph + (size_t)code * FOUT)
                                          : (ash + (size_t)(code - PP) * FOUT);
            float a = tb[g];
            float t = aacc[m][j][reg];
            wv[reg] = t;
            float ev = t * a;
            ev = (ev >= 0.f) ? ev : NEGS * ev;
            e[reg] = ev;
            mx = fmaxf(mx, ev);
          }
          mx = fmaxf(mx, __shfl_xor(mx, 16, 64));
          mx = fmaxf(mx, __shfl_xor(mx, 32, 64));
          float ssum = 0.f;
#pragma unroll
          for (int reg = 0; reg < 4; ++reg) {
            float pe = __expf(e[reg] - mx);
            e[reg] = pe;
            ssum += pe;
          }
          ssum += __shfl_xor(ssum, 16, 64);
          ssum += __shfl_xor(ssum, 32, 64);
          float inv = 1.f / ssum;
          float o = 0.f;
#pragma unroll
          for (int reg = 0; reg < 4; ++reg) {
            float u = e[reg] * inv * wv[reg];
            o += (u > 0.f) ? u : (__expf(u) - 1.f);
          }
          o += __shfl_xor(o, 16, 64);
          o += __shfl_xor(o, 32, 64);
          if (lane < 16) {
            size_t oc = (size_t)pg * 2048 + ooff + h * FOUT + g;
            unsigned short hi = bfh(o);
            xh[oc] = hi;
            xl[oc] = bfh(o - bff(hi));
          }
        }
      }
    }
  }
}

// ---------------------------------------------------------------- conv5 GEMM (MFMA, 8 waves)
// leaky(bn(X[4096][2048] @ B[2048][1024])), fused column max/sum partials per block.
__global__ __launch_bounds__(512, 3) void k_gemm5_m(const unsigned short* __restrict__ xh,
                                                    const unsigned short* __restrict__ xl,
                                                    const unsigned short* __restrict__ bph,
                                                    const unsigned short* __restrict__ bpl,
                                                    const float* __restrict__ g5,
                                                    const float* __restrict__ b5,
                                                    float* __restrict__ pmax,
                                                    float* __restrict__ psum) {
  __shared__ alignas(16) char s_mem[32768];
  int tid = threadIdx.x;
  int lane = tid & 63;
  int w = tid >> 6;
  int lg = lane >> 4;
  int ln = lane & 15;
  int bm = blockIdx.x, bn = blockIdx.y;
  int wm = w >> 2, wn = w & 3;
  f32x4 acc[4][2];
#pragma unroll
  for (int m = 0; m < 4; ++m)
#pragma unroll
    for (int j = 0; j < 2; ++j) acc[m][j] = (f32x4){0.f, 0.f, 0.f, 0.f};

  int sr = tid >> 2;
  int sq = tid & 3;
  int swz_s = (sr & 7) << 4;
  int wby0 = sr * 128 + ((sq * 32) ^ swz_s);
  int wby1 = sr * 128 + ((sq * 32 + 16) ^ swz_s);
  const unsigned short* gH = xh + (size_t)(bm * 128 + sr) * 2048 + sq * 16;
  const unsigned short* gL = xl + (size_t)(bm * 128 + sr) * 2048 + sq * 16;
  u16x8 h0 = *(const u16x8*)(gH);
  u16x8 h1 = *(const u16x8*)(gH + 8);
  u16x8 l0 = *(const u16x8*)(gL);
  u16x8 l1 = *(const u16x8*)(gL + 8);

  for (int ch = 0; ch < 32; ++ch) {
    *(u16x8*)(s_mem + wby0) = h0;
    *(u16x8*)(s_mem + wby1) = h1;
    *(u16x8*)(s_mem + 16384 + wby0) = l0;
    *(u16x8*)(s_mem + 16384 + wby1) = l1;
    __syncthreads();
    if (ch + 1 < 32) {
      h0 = *(const u16x8*)(gH + (ch + 1) * 64);
      h1 = *(const u16x8*)(gH + (ch + 1) * 64 + 8);
      l0 = *(const u16x8*)(gL + (ch + 1) * 64);
      l1 = *(const u16x8*)(gL + (ch + 1) * 64 + 8);
    }
#pragma unroll
    for (int ks = 0; ks < 2; ++ks) {
      s16x8 ah[4], al[4];
#pragma unroll
      for (int m = 0; m < 4; ++m) {
        int row = wm * 64 + m * 16 + ln;
        int by = row * 128 + ((ks * 64 + lg * 16) ^ ((row & 7) << 4));
        ah[m] = *(const s16x8*)(s_mem + by);
        al[m] = *(const s16x8*)(s_mem + 16384 + by);
      }
      int kb = ch * 2 + ks;
#pragma unroll
      for (int j = 0; j < 2; ++j) {
        size_t fo = ((size_t)(bn * 8 + wn * 2 + j) * 64 + kb) * 64 + lane;
        s16x8 bh = ((const s16x8*)bph)[fo];
        s16x8 bl = ((const s16x8*)bpl)[fo];
#pragma unroll
        for (int m = 0; m < 4; ++m) {
          acc[m][j] = mfma16(ah[m], bh, acc[m][j]);
          acc[m][j] = mfma16(al[m], bh, acc[m][j]);
          acc[m][j] = mfma16(ah[m], bl, acc[m][j]);
        }
      }
    }
    __syncthreads();
  }

  // epilogue: BN + leaky, per-column (over this block's 128 rows) max & sum
  float cmax[2], csum[2];
#pragma unroll
  for (int j = 0; j < 2; ++j) {
    int g = bn * 128 + wn * 32 + j * 16 + ln;
    float sc = g5[g] * INVS;
    float bs = b5[g];
    float mx = -3.0e38f, sm = 0.f;
#pragma unroll
    for (int m = 0; m < 4; ++m)
#pragma unroll
      for (int reg = 0; reg < 4; ++reg) {
        float v = acc[m][j][reg] * sc + bs;
        v = (v >= 0.f) ? v : NEGS * v;
        mx = fmaxf(mx, v);
        sm += v;
      }
    mx = fmaxf(mx, __shfl_xor(mx, 16, 64));
    mx = fmaxf(mx, __shfl_xor(mx, 32, 64));
    sm += __shfl_xor(sm, 16, 64);
    sm += __shfl_xor(sm, 32, 64);
    cmax[j] = mx;
    csum[j] = sm;
  }
  float* s_f = (float*)s_mem;  // [2 wm][128 col][2]
  if (lg == 0) {
#pragma unroll
    for (int j = 0; j < 2; ++j) {
      int col = wn * 32 + j * 16 + ln;
      s_f[(wm * 128 + col) * 2 + 0] = cmax[j];
      s_f[(wm * 128 + col) * 2 + 1] = csum[j];
    }
  }
  __syncthreads();
  if (tid < 128) {
    float mx = fmaxf(s_f[tid * 2], s_f[(128 + tid) * 2]);
    float sm = s_f[tid * 2 + 1] + s_f[(128 + tid) * 2 + 1];
    pmax[(size_t)bm * 1024 + bn * 128 + tid] = mx;
    psum[(size_t)bm * 1024 + bn * 128 + tid] = sm;
  }
}

// ---------------------------------------------------------------- feat + head
__global__ __launch_bounds__(256) void k_feat(const float* __restrict__ pmax,
                                              const float* __restrict__ psum,
                                              float* __restrict__ feat) {
  int t = blockIdx.x * 256 + threadIdx.x;
  if (t >= BB * 1024) return;
  int b = t >> 10, o = t & 1023;
  float mx = -3.0e38f, sm = 0.f;
  for (int i = 0; i < 16; ++i) {
    mx = fmaxf(mx, pmax[(size_t)(b * 16 + i) * 1024 + o]);
    sm += psum[(size_t)(b * 16 + i) * 1024 + o];
  }
  feat[b * 2048 + o] = mx;
  feat[b * 2048 + 1024 + o] = sm * (1.0f / NN);
}

template <bool HASB, bool DOBN, bool ACT>
__global__ __launch_bounds__(256) void k_head(const float* __restrict__ X,
                                              const float* __restrict__ Wm,
                                              const float* __restrict__ bias,
                                              const float* __restrict__ g,
                                              const float* __restrict__ bb,
                                              float* __restrict__ Y, int IN, int ON) {
  int gt = blockIdx.x * 256 + threadIdx.x;
  int w = gt >> 6, lane = gt & 63;
  if (w >= BB * ON) return;
  int b = w / ON, o = w - b * ON;
  const float* x = X + (size_t)b * IN;
  const float* wr = Wm + (size_t)o * IN;
  float s = 0.f;
  for (int c = lane; c < IN; c += 64) s += x[c] * wr[c];
#pragma unroll
  for (int off = 32; off > 0; off >>= 1) s += __shfl_down(s, off, 64);
  if (lane == 0) {
    if (HASB) s += bias[o];
    if (DOBN) s = s * INVS * g[o] + bb[o];
    if (ACT) s = (s >= 0.f) ? s : NEGS * s;
    Y[(size_t)b * ON + o] = s;
  }
}

// ---------------------------------------------------------------- launch
extern "C" void kernel_launch(void* const* d_in, const int* in_sizes, int n_in,
                              void* d_out, int out_size, void* d_ws, size_t ws_size,
                              hipStream_t stream) {
  const float* pos = (const float*)d_in[0];
  const int* types = (const int*)d_in[1];
  const float* conv1_w = (const float*)d_in[2];
  const float* bn1_g = (const float*)d_in[3];
  const float* bn1_b = (const float*)d_in[4];
  const float* W1 = (const float*)d_in[5];
  const float* ap1 = (const float*)d_in[6];
  const float* as1 = (const float*)d_in[7];
  const float* conv2_w = (const float*)d_in[8];
  const float* bn2_g = (const float*)d_in[9];
  const float* bn2_b = (const float*)d_in[10];
  const float* W2 = (const float*)d_in[11];
  const float* ap2 = (const float*)d_in[12];
  const float* as2 = (const float*)d_in[13];
  const float* conv3_w = (const float*)d_in[14];
  const float* bn3_g = (const float*)d_in[15];
  const float* bn3_b = (const float*)d_in[16];
  const float* W3 = (const float*)d_in[17];
  const float* ap3 = (const float*)d_in[18];
  const float* as3 = (const float*)d_in[19];
  const float* conv4_w = (const float*)d_in[20];
  const float* bn4_g = (const float*)d_in[21];
  const float* bn4_b = (const float*)d_in[22];
  const float* W4 = (const float*)d_in[23];
  const float* ap4 = (const float*)d_in[24];
  const float* as4 = (const float*)d_in[25];
  const float* conv5_w = (const float*)d_in[26];
  const float* bn5_g = (const float*)d_in[27];
  const float* bn5_b = (const float*)d_in[28];
  const float* lin1_w = (const float*)d_in[29];
  const float* bn6_g = (const float*)d_in[30];
  const float* bn6_b = (const float*)d_in[31];
  const float* lin2_w = (const float*)d_in[32];
  const float* lin2_b = (const float*)d_in[33];
  const float* bn7_g = (const float*)d_in[34];
  const float* bn7_b = (const float*)d_in[35];
  const float* lin3_w = (const float*)d_in[36];
  const float* lin3_b = (const float*)d_in[37];
  (void)in_sizes; (void)n_in; (void)out_size; (void)ws_size;

  float* ws = (float*)d_ws;
  size_t off = 0;
  auto take = [&](size_t nf) {
    float* p = ws + off;
    off += (nf + 63) & ~(size_t)63;
    return p;
  };
  auto takeu = [&](size_t nu) { return (unsigned short*)take((nu + 1) / 2); };

  int* idx = (int*)take(BB * NN * KK);
  int* acode = (int*)take(BB * NN * KK);
  float* rel = take((size_t)BB * NN * KK * 2);
  unsigned short* xh = takeu((size_t)BB * NN * 2048);
  unsigned short* xl = takeu((size_t)BB * NN * 2048);
  float* pmax = take(32 * 1024);
  float* psum = take(32 * 1024);
  float* feat = take(BB * 2048);
  float* h1 = take(BB * 512);
  float* h2 = take(BB * 256);
  unsigned short* c1h = takeu(64 * 64);
  unsigned short* c1l = takeu(64 * 64);
  unsigned short* c2h = takeu(512 * 64);
  unsigned short* c2l = takeu(512 * 64);
  unsigned short* c3h = takeu(512 * 128);
  unsigned short* c3l = takeu(512 * 128);
  unsigned short* c4h = takeu(1024 * 256);
  unsigned short* c4l = takeu(1024 * 256);
  unsigned short* a1h = takeu(4 * 64 * 64);
  unsigned short* a1l = takeu(4 * 64 * 64);
  unsigned short* a2h = takeu(4 * 64 * 64);
  unsigned short* a2l = takeu(4 * 64 * 64);
  unsigned short* a3h = takeu(4 * 128 * 128);
  unsigned short* a3l = takeu(4 * 128 * 128);
  unsigned short* a4h = takeu(4 * 256 * 256);
  unsigned short* a4l = takeu(4 * 256 * 256);
  unsigned short* g5h = takeu((size_t)2048 * 1024);
  unsigned short* g5l = takeu((size_t)2048 * 1024);

  dim3 blk(256);
  dim3 blk5(512);
  k_pack<<<dim3(2, 1), blk, 0, stream>>>(conv1_w, c1h, c1l, 2, 4, 64, 0, 1, 0, 0);
  k_pack<<<dim3(16, 1), blk, 0, stream>>>(conv2_w, c2h, c2l, 16, 4, 512, 256, 1, 0, 0);
  k_pack<<<dim3(32, 1), blk, 0, stream>>>(conv3_w, c3h, c3l, 16, 8, 512, 256, 1, 0, 0);
  k_pack<<<dim3(128, 1), blk, 0, stream>>>(conv4_w, c4h, c4l, 32, 16, 1024, 512, 1, 0, 0);
  k_pack<<<dim3(2, 4), blk, 0, stream>>>(W1, a1h, a1l, 2, 4, 64, 0, 0, 64 * 64, 64 * 64);
  k_pack<<<dim3(2, 4), blk, 0, stream>>>(W2, a2h, a2l, 2, 4, 64, 0, 0, 64 * 64, 64 * 64);
  k_pack<<<dim3(8, 4), blk, 0, stream>>>(W3, a3h, a3l, 4, 8, 128, 0, 0, 128 * 128, 128 * 128);
  k_pack<<<dim3(32, 4), blk, 0, stream>>>(W4, a4h, a4l, 8, 16, 256, 0, 0, 256 * 256, 256 * 256);
  k_pack<<<dim3(1024, 1), blk, 0, stream>>>(conv5_w, g5h, g5l, 64, 64, 2048, 0, 1, 0, 0);

  k_ballquery<<<dim3(BB * NN / 4), blk, 0, stream>>>(pos, types, idx, acode, rel);

  k_layer_m<64, 64, true><<<dim3(BB * NN / 4), blk5, 0, stream>>>(
      xh, xl, 0, rel, idx, acode, c1h, c1l, a1h, a1l, bn1_g, bn1_b, ap1, as1, 0);
  k_layer_m<256, 64, false><<<dim3(BB * NN / 4), blk5, 0, stream>>>(
      xh, xl, 0, rel, idx, acode, c2h, c2l, a2h, a2l, bn2_g, bn2_b, ap2, as2, 256);
  k_layer_m<256, 128, false><<<dim3(BB * NN / 4), blk5, 0, stream>>>(
      xh, xl, 256, rel, idx, acode, c3h, c3l, a3h, a3l, bn3_g, bn3_b, ap3, as3, 512);
  k_layer_m<512, 256, false><<<dim3(BB * NN / 4), blk5, 0, stream>>>(
      xh, xl, 512, rel, idx, acode, c4h, c4l, a4h, a4l, bn4_g, bn4_b, ap4, as4, 1024);

  k_gemm5_m<<<dim3(32, 8), blk5, 0, stream>>>(xh, xl, g5h, g5l, bn5_g, bn5_b, pmax, psum);
  k_feat<<<dim3(8), blk, 0, stream>>>(pmax, psum, feat);
  k_head<false, true, true><<<dim3(BB * 512 * 64 / 256), blk, 0, stream>>>(
      feat, lin1_w, nullptr, bn6_g, bn6_b, h1, 2048, 512);
  k_head<true, true, true><<<dim3(BB * 256 * 64 / 256), blk, 0, stream>>>(
      h1, lin2_w, lin2_b, bn7_g, bn7_b, h2, 512, 256);
  k_head<true, false, false><<<dim3(1), blk, 0, stream>>>(
      h2, lin3_w, lin3_b, nullptr, nullptr, (float*)d_out, 256, 2);
}

// Round 4
// 597.454 us; speedup vs baseline: 3.4087x; 1.5317x over previous
//
#include <hip/hip_runtime.h>
#include <math.h>

#define BB 2
#define NN 2048
#define KK 16
#define HH 4
#define CC 8
#define PP 36
#define NEGS 0.2f
#define INVS 0.9999950000374997f  // 1/sqrt(1+1e-5)

typedef __attribute__((ext_vector_type(8))) short s16x8;
typedef __attribute__((ext_vector_type(8))) unsigned short u16x8;
typedef __attribute__((ext_vector_type(4))) float f32x4;

__device__ inline unsigned short bfh(float x) {
  unsigned u = __float_as_uint(x);
  return (unsigned short)((u + 0x7FFFu + ((u >> 16) & 1u)) >> 16);
}
__device__ inline float bff(unsigned short h) {
  return __uint_as_float(((unsigned)h) << 16);
}
__device__ inline f32x4 mfma16(s16x8 a, s16x8 b, f32x4 c) {
  return __builtin_amdgcn_mfma_f32_16x16x32_bf16(a, b, c, 0, 0, 0);
}

// ---------------------------------------------------------------- ball query
__global__ __launch_bounds__(256) void k_ballquery(const float* __restrict__ pos,
                                                   const int* __restrict__ types,
                                                   int* __restrict__ idxg,
                                                   int* __restrict__ acode,
                                                   float* __restrict__ rel) {
  __shared__ int s_buf[4][KK];
  const float r2 = (float)(0.08 * 0.08);
  int wslot = threadIdx.x >> 6;
  int lane = threadIdx.x & 63;
  int wg = blockIdx.x * 4 + wslot;
  int b = wg / NN, n = wg - b * NN;
  const float* pb = pos + (size_t)b * NN * 2;
  float px = pb[n * 2 + 0], py = pb[n * 2 + 1];
  float sqn = px * px + py * py;
  unsigned mask = 0u;
  int base = lane * 32;
  for (int j = 0; j < 32; ++j) {
    float qx = pb[(base + j) * 2 + 0], qy = pb[(base + j) * 2 + 1];
    float sqm = qx * qx + qy * qy;
    float d = sqn + sqm - 2.0f * (px * qx + py * qy);
    if (d <= r2) mask |= (1u << j);
  }
  int cnt = __popc(mask);
  int inc = cnt;
#pragma unroll
  for (int off = 1; off < 64; off <<= 1) {
    int v = __shfl_up(inc, off, 64);
    if (lane >= off) inc += v;
  }
  int total = __shfl(inc, 63, 64);
  int excl = inc - cnt;
  unsigned mm = mask;
  int p = excl;
  while (mm && p < KK) {
    int j = __ffs(mm) - 1;
    mm &= mm - 1u;
    s_buf[wslot][p] = base + j;
    ++p;
  }
  __syncthreads();
  int tc = total < KK ? total : KK;
  if (lane < KK) {
    int m0 = s_buf[wslot][0];
    int mk = (lane < tc) ? s_buf[wslot][lane] : m0;
    idxg[wg * KK + lane] = mk;
    int core = types[b * NN + n];
    int tg = types[b * NN + mk];
    int s0 = tg < core ? tg : core;
    int s1 = tg < core ? core : tg;
    int code = s0 * CC - (s0 * (s0 - 1)) / 2 + (s1 - s0);
    if (lane == 0 && tg < core) code = PP + core;
    acode[wg * KK + lane] = code;
    rel[(wg * KK + lane) * 2 + 0] = pb[mk * 2 + 0] - px;
    rel[(wg * KK + lane) * 2 + 1] = pb[mk * 2 + 1] - py;
  }
}

// ---------------------------------------------------------------- weight pack
// frag layout: elem(kb,nt,l,i) = B[kb*32 + (l>>4)*8 + i][nt*16 + (l&15)]
__global__ __launch_bounds__(256) void k_pack(const float* __restrict__ src,
                                              unsigned short* __restrict__ dh,
                                              unsigned short* __restrict__ dl,
                                              int KB, int NT, int srcld, int Cdiff,
                                              int mode, int sstride, int dstride) {
  src += (size_t)blockIdx.y * sstride;
  dh += (size_t)blockIdx.y * dstride;
  dl += (size_t)blockIdx.y * dstride;
  int f = blockIdx.x * 256 + threadIdx.x;
  int total = KB * NT * 64;
  if (f >= total) return;
  int l = f & 63;
  int t2 = f >> 6;
  int n = (t2 / KB) * 16 + (l & 15);
  int k0 = (t2 % KB) * 32 + ((l >> 4) * 8);
  size_t o = (size_t)t2 * 512 + (size_t)l * 8;
#pragma unroll
  for (int i = 0; i < 8; ++i) {
    int k = k0 + i;
    float v;
    if (mode == 0) {
      v = src[(size_t)k * srcld + n];
    } else {
      v = src[(size_t)n * srcld + k];
      if (Cdiff > 0 && k >= Cdiff) v -= src[(size_t)n * srcld + k - Cdiff];
    }
    unsigned short hi = bfh(v);
    dh[o + i] = hi;
    dl[o + i] = bfh(v - bff(hi));
  }
}

// ---------------------------------------------------------------- fused layer (MFMA, 8 waves)
// Block = 4 points (64 neighbor rows), 512 threads.
// Conv: [64 x K_TOT] @ [K_TOT x FOUT], reg-staged pipeline, x/y LDS union.
// Attention: wave = (head, N-half), JW=2 n-tiles per pass (32 AGPR acc -> no spill
// under the (512,3) 170-reg cap; R3's JW=4 spilled 0.6GB/dispatch to scratch).
template <int CPREV, int FOUT, bool L1M>
__global__ __launch_bounds__(512, 3) void k_layer_m(
    unsigned short* xh, unsigned short* xl, int xoff,
    const float* __restrict__ rel, const int* __restrict__ idx,
    const int* __restrict__ acode,
    const unsigned short* __restrict__ convh, const unsigned short* __restrict__ convl,
    const unsigned short* __restrict__ attnh, const unsigned short* __restrict__ attnl,
    const float* __restrict__ bng, const float* __restrict__ bnb,
    const float* __restrict__ ap, const float* __restrict__ as_, int ooff) {
  constexpr int K_TOT = L1M ? CPREV : 2 * CPREV;
  constexpr int NCH = K_TOT / 64;
  constexpr int KB = K_TOT / 32;
  constexpr int NT = FOUT / 16;
  constexpr int NT_W = NT / 4;          // conv n-tiles per wave (2x4 wave grid)
  constexpr int NTW_A = NT / 2;         // attn n-tiles per wave (head x half)
  constexpr int JW = (NTW_A > 2) ? 2 : NTW_A;   // small acc tile: avoid spill
  constexpr int NPASS = NTW_A / JW;
  constexpr int KBA = FOUT / 32;
  constexpr int YH_BYTES = 64 * FOUT * 2;  // one y plane
  constexpr int S_BYTES = (2 * YH_BYTES > 16384) ? 2 * YH_BYTES : 16384;

  __shared__ alignas(16) char s_mem[S_BYTES];  // union: x-stage (16KB) / y (hi|lo)
  __shared__ int s_gsrc[64];
  __shared__ int s_code[64];

  int tid = threadIdx.x;
  int lane = tid & 63;
  int w = tid >> 6;
  int lg = lane >> 4;
  int ln = lane & 15;
  int pgbase = blockIdx.x * 4;

  if (tid < 64) {
    int pg = pgbase + (tid >> 4);
    int b = pg >> 11;
    s_gsrc[tid] = b * 2048 + idx[pg * KK + (tid & 15)];
    s_code[tid] = acode[pg * KK + (tid & 15)];
  }
  __syncthreads();

  // staging geometry: thread -> (row sr, 8-channel group sq)
  int sr = tid >> 3;
  int sq = tid & 7;
  int wbyH = sr * 128 + ((sq * 16) ^ ((sr & 7) << 4));

  // conv wave roles: 2 row-halves x 4 col-quarters
  int wr = w >> 2, wc = w & 3;
  f32x4 cacc[2][NT_W];
#pragma unroll
  for (int m = 0; m < 2; ++m)
#pragma unroll
    for (int j = 0; j < NT_W; ++j) cacc[m][j] = (f32x4){0.f, 0.f, 0.f, 0.f};

  auto compute_chunk = [&](int ch) {
#pragma unroll
    for (int ks = 0; ks < 2; ++ks) {
      s16x8 ah[2], al[2];
#pragma unroll
      for (int m = 0; m < 2; ++m) {
        int row = wr * 32 + m * 16 + ln;
        int by = row * 128 + ((ks * 64 + lg * 16) ^ ((row & 7) << 4));
        ah[m] = *(const s16x8*)(s_mem + by);
        al[m] = *(const s16x8*)(s_mem + 8192 + by);
      }
      int kb = ch * 2 + ks;
#pragma unroll
      for (int j = 0; j < NT_W; ++j) {
        size_t fo = ((size_t)(wc * NT_W + j) * KB + kb) * 64 + lane;
        s16x8 bh = ((const s16x8*)convh)[fo];
        s16x8 bl = ((const s16x8*)convl)[fo];
#pragma unroll
        for (int m = 0; m < 2; ++m) {
          cacc[m][j] = mfma16(ah[m], bh, cacc[m][j]);
          cacc[m][j] = mfma16(al[m], bh, cacc[m][j]);
          cacc[m][j] = mfma16(ah[m], bl, cacc[m][j]);
        }
      }
    }
  };

  if constexpr (L1M) {
    // compute PE in-place, single chunk
    int pg = pgbase + (sr >> 4);
    float rc = rel[((size_t)pg * KK + (sr & 15)) * 2 + (sq >> 2)];
    bool isSin = (sq & 3) < 2;
    unsigned short hb[8], lb[8];
#pragma unroll
    for (int i = 0; i < 8; ++i) {
      int j = (sq & 3) * 8 + i;
      int fidx = j & 15;
      float freq = exp2f(-(float)fidx * 0.8304820237218406f);  // 10000^(-fidx/16)
      float ang = rc * freq;
      float v = isSin ? __sinf(ang) : __cosf(ang);
      unsigned short hi = bfh(v);
      hb[i] = hi;
      lb[i] = bfh(v - bff(hi));
    }
    *(u16x8*)(s_mem + wbyH) = *(u16x8*)hb;
    *(u16x8*)(s_mem + 8192 + wbyH) = *(u16x8*)lb;
    __syncthreads();
    compute_chunk(0);
    __syncthreads();
  } else {
    const unsigned short* gAh = xh + (size_t)s_gsrc[sr] * 2048 + xoff + sq * 8;
    const unsigned short* gAl = xl + (size_t)s_gsrc[sr] * 2048 + xoff + sq * 8;
    const unsigned short* gCh = xh + (size_t)(pgbase + (sr >> 4)) * 2048 + xoff + sq * 8;
    const unsigned short* gCl = xl + (size_t)(pgbase + (sr >> 4)) * 2048 + xoff + sq * 8;
    auto srcp = [&](int ch, int plane) -> const unsigned short* {
      int c0 = ch * 64;
      bool aug = c0 >= CPREV;
      int coff = aug ? c0 - CPREV : c0;
      const unsigned short* p = plane ? (aug ? gCl : gAl) : (aug ? gCh : gAh);
      return p + coff;
    };
    u16x8 hv = *(const u16x8*)srcp(0, 0);
    u16x8 lv = *(const u16x8*)srcp(0, 1);
    for (int ch = 0; ch < NCH; ++ch) {
      *(u16x8*)(s_mem + wbyH) = hv;
      *(u16x8*)(s_mem + 8192 + wbyH) = lv;
      __syncthreads();
      if (ch + 1 < NCH) {  // prefetch: loads overlap this chunk's MFMA
        hv = *(const u16x8*)srcp(ch + 1, 0);
        lv = *(const u16x8*)srcp(ch + 1, 1);
      }
      compute_chunk(ch);
      __syncthreads();
    }
  }

  // conv epilogue: BN + leaky -> y (overlays x buffer; conv loop ended w/ barrier)
#pragma unroll
  for (int j = 0; j < NT_W; ++j) {
    int g = (wc * NT_W + j) * 16 + ln;
    float sc = bng[g] * INVS;
    float bs = bnb[g];
#pragma unroll
    for (int m = 0; m < 2; ++m) {
#pragma unroll
      for (int reg = 0; reg < 4; ++reg) {
        int row = wr * 32 + m * 16 + lg * 4 + reg;
        float v = cacc[m][j][reg] * sc + bs;
        v = (v >= 0.f) ? v : NEGS * v;
        unsigned short hi = bfh(v);
        unsigned short lo = bfh(v - bff(hi));
        int by = row * (FOUT * 2) + ((g * 2) ^ ((row & 7) << 4));
        *(unsigned short*)(s_mem + by) = hi;
        *(unsigned short*)(s_mem + YH_BYTES + by) = lo;
      }
    }
  }
  __syncthreads();

  // attention: wave = (head h, N-half nh)
  {
    int h = w >> 1, nh = w & 1;
    const s16x8* wph = (const s16x8*)(attnh + (size_t)h * FOUT * FOUT);
    const s16x8* wpl = (const s16x8*)(attnl + (size_t)h * FOUT * FOUT);
    const float* aph = ap + (size_t)h * PP * FOUT;
    const float* ash = as_ + (size_t)h * CC * FOUT;
    for (int pass = 0; pass < NPASS; ++pass) {
      f32x4 aacc[4][JW];
#pragma unroll
      for (int m = 0; m < 4; ++m)
#pragma unroll
        for (int j = 0; j < JW; ++j) aacc[m][j] = (f32x4){0.f, 0.f, 0.f, 0.f};
#pragma unroll 2
      for (int kb = 0; kb < KBA; ++kb) {
        s16x8 ah[4], al[4];
#pragma unroll
        for (int m = 0; m < 4; ++m) {
          int row = m * 16 + ln;
          int by = row * (FOUT * 2) + ((kb * 64 + lg * 16) ^ ((row & 7) << 4));
          ah[m] = *(const s16x8*)(s_mem + by);
          al[m] = *(const s16x8*)(s_mem + YH_BYTES + by);
        }
#pragma unroll
        for (int j = 0; j < JW; ++j) {
          int nt = nh * NTW_A + pass * JW + j;
          size_t fo = ((size_t)nt * KBA + kb) * 64 + lane;
          s16x8 bh = wph[fo];
          s16x8 bl = wpl[fo];
#pragma unroll
          for (int m = 0; m < 4; ++m) {
            aacc[m][j] = mfma16(ah[m], bh, aacc[m][j]);
            aacc[m][j] = mfma16(al[m], bh, aacc[m][j]);
            aacc[m][j] = mfma16(ah[m], bl, aacc[m][j]);
          }
        }
      }
#pragma unroll
      for (int m = 0; m < 4; ++m) {
        int pg = pgbase + m;
#pragma unroll
        for (int j = 0; j < JW; ++j) {
          int nt = nh * NTW_A + pass * JW + j;
          int g = nt * 16 + ln;
          float wv[4], e[4];
          float mx = -3.0e38f;
#pragma unroll
          for (int reg = 0; reg < 4; ++reg) {
            int code = s_code[m * 16 + lg * 4 + reg];
            const float* tb = (code < PP) ? (aph + (size_t)code * FOUT)
                                          : (ash + (size_t)(code - PP) * FOUT);
            float a = tb[g];
            float t = aacc[m][j][reg];
            wv[reg] = t;
            float ev = t * a;
            ev = (ev >= 0.f) ? ev : NEGS * ev;
            e[reg] = ev;
            mx = fmaxf(mx, ev);
          }
          mx = fmaxf(mx, __shfl_xor(mx, 16, 64));
          mx = fmaxf(mx, __shfl_xor(mx, 32, 64));
          float ssum = 0.f;
#pragma unroll
          for (int reg = 0; reg < 4; ++reg) {
            float pe = __expf(e[reg] - mx);
            e[reg] = pe;
            ssum += pe;
          }
          ssum += __shfl_xor(ssum, 16, 64);
          ssum += __shfl_xor(ssum, 32, 64);
          float inv = 1.f / ssum;
          float o = 0.f;
#pragma unroll
          for (int reg = 0; reg < 4; ++reg) {
            float u = e[reg] * inv * wv[reg];
            o += (u > 0.f) ? u : (__expf(u) - 1.f);
          }
          o += __shfl_xor(o, 16, 64);
          o += __shfl_xor(o, 32, 64);
          if (lane < 16) {
            size_t oc = (size_t)pg * 2048 + ooff + h * FOUT + g;
            unsigned short hi = bfh(o);
            xh[oc] = hi;
            xl[oc] = bfh(o - bff(hi));
          }
        }
      }
    }
  }
}

// ---------------------------------------------------------------- conv5 GEMM (MFMA, 8 waves)
// leaky(bn(X[4096][2048] @ B[2048][1024])), fused column max/sum partials per block.
__global__ __launch_bounds__(512, 2) void k_gemm5_m(const unsigned short* __restrict__ xh,
                                                    const unsigned short* __restrict__ xl,
                                                    const unsigned short* __restrict__ bph,
                                                    const unsigned short* __restrict__ bpl,
                                                    const float* __restrict__ g5,
                                                    const float* __restrict__ b5,
                                                    float* __restrict__ pmax,
                                                    float* __restrict__ psum) {
  __shared__ alignas(16) char s_mem[32768];
  int tid = threadIdx.x;
  int lane = tid & 63;
  int w = tid >> 6;
  int lg = lane >> 4;
  int ln = lane & 15;
  int bm = blockIdx.x, bn = blockIdx.y;
  int wm = w >> 2, wn = w & 3;
  f32x4 acc[4][2];
#pragma unroll
  for (int m = 0; m < 4; ++m)
#pragma unroll
    for (int j = 0; j < 2; ++j) acc[m][j] = (f32x4){0.f, 0.f, 0.f, 0.f};

  int sr = tid >> 2;
  int sq = tid & 3;
  int swz_s = (sr & 7) << 4;
  int wby0 = sr * 128 + ((sq * 32) ^ swz_s);
  int wby1 = sr * 128 + ((sq * 32 + 16) ^ swz_s);
  const unsigned short* gH = xh + (size_t)(bm * 128 + sr) * 2048 + sq * 16;
  const unsigned short* gL = xl + (size_t)(bm * 128 + sr) * 2048 + sq * 16;
  u16x8 h0 = *(const u16x8*)(gH);
  u16x8 h1 = *(const u16x8*)(gH + 8);
  u16x8 l0 = *(const u16x8*)(gL);
  u16x8 l1 = *(const u16x8*)(gL + 8);

  for (int ch = 0; ch < 32; ++ch) {
    *(u16x8*)(s_mem + wby0) = h0;
    *(u16x8*)(s_mem + wby1) = h1;
    *(u16x8*)(s_mem + 16384 + wby0) = l0;
    *(u16x8*)(s_mem + 16384 + wby1) = l1;
    __syncthreads();
    if (ch + 1 < 32) {
      h0 = *(const u16x8*)(gH + (ch + 1) * 64);
      h1 = *(const u16x8*)(gH + (ch + 1) * 64 + 8);
      l0 = *(const u16x8*)(gL + (ch + 1) * 64);
      l1 = *(const u16x8*)(gL + (ch + 1) * 64 + 8);
    }
#pragma unroll
    for (int ks = 0; ks < 2; ++ks) {
      s16x8 ah[4], al[4];
#pragma unroll
      for (int m = 0; m < 4; ++m) {
        int row = wm * 64 + m * 16 + ln;
        int by = row * 128 + ((ks * 64 + lg * 16) ^ ((row & 7) << 4));
        ah[m] = *(const s16x8*)(s_mem + by);
        al[m] = *(const s16x8*)(s_mem + 16384 + by);
      }
      int kb = ch * 2 + ks;
#pragma unroll
      for (int j = 0; j < 2; ++j) {
        size_t fo = ((size_t)(bn * 8 + wn * 2 + j) * 64 + kb) * 64 + lane;
        s16x8 bh = ((const s16x8*)bph)[fo];
        s16x8 bl = ((const s16x8*)bpl)[fo];
#pragma unroll
        for (int m = 0; m < 4; ++m) {
          acc[m][j] = mfma16(ah[m], bh, acc[m][j]);
          acc[m][j] = mfma16(al[m], bh, acc[m][j]);
          acc[m][j] = mfma16(ah[m], bl, acc[m][j]);
        }
      }
    }
    __syncthreads();
  }

  // epilogue: BN + leaky, per-column (over this block's 128 rows) max & sum
  float cmax[2], csum[2];
#pragma unroll
  for (int j = 0; j < 2; ++j) {
    int g = bn * 128 + wn * 32 + j * 16 + ln;
    float sc = g5[g] * INVS;
    float bs = b5[g];
    float mx = -3.0e38f, sm = 0.f;
#pragma unroll
    for (int m = 0; m < 4; ++m)
#pragma unroll
      for (int reg = 0; reg < 4; ++reg) {
        float v = acc[m][j][reg] * sc + bs;
        v = (v >= 0.f) ? v : NEGS * v;
        mx = fmaxf(mx, v);
        sm += v;
      }
    mx = fmaxf(mx, __shfl_xor(mx, 16, 64));
    mx = fmaxf(mx, __shfl_xor(mx, 32, 64));
    sm += __shfl_xor(sm, 16, 64);
    sm += __shfl_xor(sm, 32, 64);
    cmax[j] = mx;
    csum[j] = sm;
  }
  float* s_f = (float*)s_mem;  // [2 wm][128 col][2]
  if (lg == 0) {
#pragma unroll
    for (int j = 0; j < 2; ++j) {
      int col = wn * 32 + j * 16 + ln;
      s_f[(wm * 128 + col) * 2 + 0] = cmax[j];
      s_f[(wm * 128 + col) * 2 + 1] = csum[j];
    }
  }
  __syncthreads();
  if (tid < 128) {
    float mx = fmaxf(s_f[tid * 2], s_f[(128 + tid) * 2]);
    float sm = s_f[tid * 2 + 1] + s_f[(128 + tid) * 2 + 1];
    pmax[(size_t)bm * 1024 + bn * 128 + tid] = mx;
    psum[(size_t)bm * 1024 + bn * 128 + tid] = sm;
  }
}

// ---------------------------------------------------------------- feat + head
__global__ __launch_bounds__(256) void k_feat(const float* __restrict__ pmax,
                                              const float* __restrict__ psum,
                                              float* __restrict__ feat) {
  int t = blockIdx.x * 256 + threadIdx.x;
  if (t >= BB * 1024) return;
  int b = t >> 10, o = t & 1023;
  float mx = -3.0e38f, sm = 0.f;
  for (int i = 0; i < 16; ++i) {
    mx = fmaxf(mx, pmax[(size_t)(b * 16 + i) * 1024 + o]);
    sm += psum[(size_t)(b * 16 + i) * 1024 + o];
  }
  feat[b * 2048 + o] = mx;
  feat[b * 2048 + 1024 + o] = sm * (1.0f / NN);
}

template <bool HASB, bool DOBN, bool ACT>
__global__ __launch_bounds__(256) void k_head(const float* __restrict__ X,
                                              const float* __restrict__ Wm,
                                              const float* __restrict__ bias,
                                              const float* __restrict__ g,
                                              const float* __restrict__ bb,
                                              float* __restrict__ Y, int IN, int ON) {
  int gt = blockIdx.x * 256 + threadIdx.x;
  int w = gt >> 6, lane = gt & 63;
  if (w >= BB * ON) return;
  int b = w / ON, o = w - b * ON;
  const float* x = X + (size_t)b * IN;
  const float* wr = Wm + (size_t)o * IN;
  float s = 0.f;
  for (int c = lane; c < IN; c += 64) s += x[c] * wr[c];
#pragma unroll
  for (int off = 32; off > 0; off >>= 1) s += __shfl_down(s, off, 64);
  if (lane == 0) {
    if (HASB) s += bias[o];
    if (DOBN) s = s * INVS * g[o] + bb[o];
    if (ACT) s = (s >= 0.f) ? s : NEGS * s;
    Y[(size_t)b * ON + o] = s;
  }
}

// ---------------------------------------------------------------- launch
extern "C" void kernel_launch(void* const* d_in, const int* in_sizes, int n_in,
                              void* d_out, int out_size, void* d_ws, size_t ws_size,
                              hipStream_t stream) {
  const float* pos = (const float*)d_in[0];
  const int* types = (const int*)d_in[1];
  const float* conv1_w = (const float*)d_in[2];
  const float* bn1_g = (const float*)d_in[3];
  const float* bn1_b = (const float*)d_in[4];
  const float* W1 = (const float*)d_in[5];
  const float* ap1 = (const float*)d_in[6];
  const float* as1 = (const float*)d_in[7];
  const float* conv2_w = (const float*)d_in[8];
  const float* bn2_g = (const float*)d_in[9];
  const float* bn2_b = (const float*)d_in[10];
  const float* W2 = (const float*)d_in[11];
  const float* ap2 = (const float*)d_in[12];
  const float* as2 = (const float*)d_in[13];
  const float* conv3_w = (const float*)d_in[14];
  const float* bn3_g = (const float*)d_in[15];
  const float* bn3_b = (const float*)d_in[16];
  const float* W3 = (const float*)d_in[17];
  const float* ap3 = (const float*)d_in[18];
  const float* as3 = (const float*)d_in[19];
  const float* conv4_w = (const float*)d_in[20];
  const float* bn4_g = (const float*)d_in[21];
  const float* bn4_b = (const float*)d_in[22];
  const float* W4 = (const float*)d_in[23];
  const float* ap4 = (const float*)d_in[24];
  const float* as4 = (const float*)d_in[25];
  const float* conv5_w = (const float*)d_in[26];
  const float* bn5_g = (const float*)d_in[27];
  const float* bn5_b = (const float*)d_in[28];
  const float* lin1_w = (const float*)d_in[29];
  const float* bn6_g = (const float*)d_in[30];
  const float* bn6_b = (const float*)d_in[31];
  const float* lin2_w = (const float*)d_in[32];
  const float* lin2_b = (const float*)d_in[33];
  const float* bn7_g = (const float*)d_in[34];
  const float* bn7_b = (const float*)d_in[35];
  const float* lin3_w = (const float*)d_in[36];
  const float* lin3_b = (const float*)d_in[37];
  (void)in_sizes; (void)n_in; (void)out_size; (void)ws_size;

  float* ws = (float*)d_ws;
  size_t off = 0;
  auto take = [&](size_t nf) {
    float* p = ws + off;
    off += (nf + 63) & ~(size_t)63;
    return p;
  };
  auto takeu = [&](size_t nu) { return (unsigned short*)take((nu + 1) / 2); };

  int* idx = (int*)take(BB * NN * KK);
  int* acode = (int*)take(BB * NN * KK);
  float* rel = take((size_t)BB * NN * KK * 2);
  unsigned short* xh = takeu((size_t)BB * NN * 2048);
  unsigned short* xl = takeu((size_t)BB * NN * 2048);
  float* pmax = take(32 * 1024);
  float* psum = take(32 * 1024);
  float* feat = take(BB * 2048);
  float* h1 = take(BB * 512);
  float* h2 = take(BB * 256);
  unsigned short* c1h = takeu(64 * 64);
  unsigned short* c1l = takeu(64 * 64);
  unsigned short* c2h = takeu(512 * 64);
  unsigned short* c2l = takeu(512 * 64);
  unsigned short* c3h = takeu(512 * 128);
  unsigned short* c3l = takeu(512 * 128);
  unsigned short* c4h = takeu(1024 * 256);
  unsigned short* c4l = takeu(1024 * 256);
  unsigned short* a1h = takeu(4 * 64 * 64);
  unsigned short* a1l = takeu(4 * 64 * 64);
  unsigned short* a2h = takeu(4 * 64 * 64);
  unsigned short* a2l = takeu(4 * 64 * 64);
  unsigned short* a3h = takeu(4 * 128 * 128);
  unsigned short* a3l = takeu(4 * 128 * 128);
  unsigned short* a4h = takeu(4 * 256 * 256);
  unsigned short* a4l = takeu(4 * 256 * 256);
  unsigned short* g5h = takeu((size_t)2048 * 1024);
  unsigned short* g5l = takeu((size_t)2048 * 1024);

  dim3 blk(256);
  dim3 blk5(512);
  k_pack<<<dim3(2, 1), blk, 0, stream>>>(conv1_w, c1h, c1l, 2, 4, 64, 0, 1, 0, 0);
  k_pack<<<dim3(16, 1), blk, 0, stream>>>(conv2_w, c2h, c2l, 16, 4, 512, 256, 1, 0, 0);
  k_pack<<<dim3(32, 1), blk, 0, stream>>>(conv3_w, c3h, c3l, 16, 8, 512, 256, 1, 0, 0);
  k_pack<<<dim3(128, 1), blk, 0, stream>>>(conv4_w, c4h, c4l, 32, 16, 1024, 512, 1, 0, 0);
  k_pack<<<dim3(2, 4), blk, 0, stream>>>(W1, a1h, a1l, 2, 4, 64, 0, 0, 64 * 64, 64 * 64);
  k_pack<<<dim3(2, 4), blk, 0, stream>>>(W2, a2h, a2l, 2, 4, 64, 0, 0, 64 * 64, 64 * 64);
  k_pack<<<dim3(8, 4), blk, 0, stream>>>(W3, a3h, a3l, 4, 8, 128, 0, 0, 128 * 128, 128 * 128);
  k_pack<<<dim3(32, 4), blk, 0, stream>>>(W4, a4h, a4l, 8, 16, 256, 0, 0, 256 * 256, 256 * 256);
  k_pack<<<dim3(1024, 1), blk, 0, stream>>>(conv5_w, g5h, g5l, 64, 64, 2048, 0, 1, 0, 0);

  k_ballquery<<<dim3(BB * NN / 4), blk, 0, stream>>>(pos, types, idx, acode, rel);

  k_layer_m<64, 64, true><<<dim3(BB * NN / 4), blk5, 0, stream>>>(
      xh, xl, 0, rel, idx, acode, c1h, c1l, a1h, a1l, bn1_g, bn1_b, ap1, as1, 0);
  k_layer_m<256, 64, false><<<dim3(BB * NN / 4), blk5, 0, stream>>>(
      xh, xl, 0, rel, idx, acode, c2h, c2l, a2h, a2l, bn2_g, bn2_b, ap2, as2, 256);
  k_layer_m<256, 128, false><<<dim3(BB * NN / 4), blk5, 0, stream>>>(
      xh, xl, 256, rel, idx, acode, c3h, c3l, a3h, a3l, bn3_g, bn3_b, ap3, as3, 512);
  k_layer_m<512, 256, false><<<dim3(BB * NN / 4), blk5, 0, stream>>>(
      xh, xl, 512, rel, idx, acode, c4h, c4l, a4h, a4l, bn4_g, bn4_b, ap4, as4, 1024);

  k_gemm5_m<<<dim3(32, 8), blk5, 0, stream>>>(xh, xl, g5h, g5l, bn5_g, bn5_b, pmax, psum);
  k_feat<<<dim3(8), blk, 0, stream>>>(pmax, psum, feat);
  k_head<false, true, true><<<dim3(BB * 512 * 64 / 256), blk, 0, stream>>>(
      feat, lin1_w, nullptr, bn6_g, bn6_b, h1, 2048, 512);
  k_head<true, true, true><<<dim3(BB * 256 * 64 / 256), blk, 0, stream>>>(
      h1, lin2_w, lin2_b, bn7_g, bn7_b, h2, 512, 256);
  k_head<true, false, false><<<dim3(1), blk, 0, stream>>>(
      h2, lin3_w, lin3_b, nullptr, nullptr, (float*)d_out, 256, 2);
}

// Round 5
// 545.116 us; speedup vs baseline: 3.7360x; 1.0960x over previous
//
#include <hip/hip_runtime.h>
#include <math.h>

#define BB 2
#define NN 2048
#define KK 16
#define HH 4
#define CC 8
#define PP 36
#define NEGS 0.2f
#define INVS 0.9999950000374997f  // 1/sqrt(1+1e-5)

typedef __attribute__((ext_vector_type(8))) short s16x8;
typedef __attribute__((ext_vector_type(8))) unsigned short u16x8;
typedef __attribute__((ext_vector_type(4))) float f32x4;

__device__ inline unsigned short bfh(float x) {
  unsigned u = __float_as_uint(x);
  return (unsigned short)((u + 0x7FFFu + ((u >> 16) & 1u)) >> 16);
}
__device__ inline float bff(unsigned short h) {
  return __uint_as_float(((unsigned)h) << 16);
}
__device__ inline f32x4 mfma16(s16x8 a, s16x8 b, f32x4 c) {
  return __builtin_amdgcn_mfma_f32_16x16x32_bf16(a, b, c, 0, 0, 0);
}

// ---------------------------------------------------------------- ball query
__global__ __launch_bounds__(256) void k_ballquery(const float* __restrict__ pos,
                                                   const int* __restrict__ types,
                                                   int* __restrict__ idxg,
                                                   int* __restrict__ acode,
                                                   float* __restrict__ rel) {
  __shared__ int s_buf[4][KK];
  const float r2 = (float)(0.08 * 0.08);
  int wslot = threadIdx.x >> 6;
  int lane = threadIdx.x & 63;
  int wg = blockIdx.x * 4 + wslot;
  int b = wg / NN, n = wg - b * NN;
  const float* pb = pos + (size_t)b * NN * 2;
  float px = pb[n * 2 + 0], py = pb[n * 2 + 1];
  float sqn = px * px + py * py;
  unsigned mask = 0u;
  int base = lane * 32;
  for (int j = 0; j < 32; ++j) {
    float qx = pb[(base + j) * 2 + 0], qy = pb[(base + j) * 2 + 1];
    float sqm = qx * qx + qy * qy;
    float d = sqn + sqm - 2.0f * (px * qx + py * qy);
    if (d <= r2) mask |= (1u << j);
  }
  int cnt = __popc(mask);
  int inc = cnt;
#pragma unroll
  for (int off = 1; off < 64; off <<= 1) {
    int v = __shfl_up(inc, off, 64);
    if (lane >= off) inc += v;
  }
  int total = __shfl(inc, 63, 64);
  int excl = inc - cnt;
  unsigned mm = mask;
  int p = excl;
  while (mm && p < KK) {
    int j = __ffs(mm) - 1;
    mm &= mm - 1u;
    s_buf[wslot][p] = base + j;
    ++p;
  }
  __syncthreads();
  int tc = total < KK ? total : KK;
  if (lane < KK) {
    int m0 = s_buf[wslot][0];
    int mk = (lane < tc) ? s_buf[wslot][lane] : m0;
    idxg[wg * KK + lane] = mk;
    int core = types[b * NN + n];
    int tg = types[b * NN + mk];
    int s0 = tg < core ? tg : core;
    int s1 = tg < core ? core : tg;
    int code = s0 * CC - (s0 * (s0 - 1)) / 2 + (s1 - s0);
    if (lane == 0 && tg < core) code = PP + core;
    acode[wg * KK + lane] = code;
    rel[(wg * KK + lane) * 2 + 0] = pb[mk * 2 + 0] - px;
    rel[(wg * KK + lane) * 2 + 1] = pb[mk * 2 + 1] - py;
  }
}

// ---------------------------------------------------------------- weight pack
// frag layout: elem(kb,nt,l,i) = B[kb*32 + (l>>4)*8 + i][nt*16 + (l&15)]
__global__ __launch_bounds__(256) void k_pack(const float* __restrict__ src,
                                              unsigned short* __restrict__ dh,
                                              unsigned short* __restrict__ dl,
                                              int KB, int NT, int srcld, int Cdiff,
                                              int mode, int sstride, int dstride) {
  src += (size_t)blockIdx.y * sstride;
  dh += (size_t)blockIdx.y * dstride;
  dl += (size_t)blockIdx.y * dstride;
  int f = blockIdx.x * 256 + threadIdx.x;
  int total = KB * NT * 64;
  if (f >= total) return;
  int l = f & 63;
  int t2 = f >> 6;
  int n = (t2 / KB) * 16 + (l & 15);
  int k0 = (t2 % KB) * 32 + ((l >> 4) * 8);
  size_t o = (size_t)t2 * 512 + (size_t)l * 8;
#pragma unroll
  for (int i = 0; i < 8; ++i) {
    int k = k0 + i;
    float v;
    if (mode == 0) {
      v = src[(size_t)k * srcld + n];
    } else {
      v = src[(size_t)n * srcld + k];
      if (Cdiff > 0 && k >= Cdiff) v -= src[(size_t)n * srcld + k - Cdiff];
    }
    unsigned short hi = bfh(v);
    dh[o + i] = hi;
    dl[o + i] = bfh(v - bff(hi));
  }
}

// ---------------------------------------------------------------- fused layer (MFMA, 8 waves)
// Block = 4 points (64 neighbor rows), 512 threads, 2 blocks/CU (128-reg cap).
// LDS tensors (x-stage, y) are FRAGMENT-MAJOR: frag(mt,kb) at ((mt*KB+kb)*64+l)*16,
// lane reads its own contiguous 16B -> zero bank conflicts (R4 swizzle was 8-way).
template <int CPREV, int FOUT, bool L1M>
__global__ __launch_bounds__(512, 4) void k_layer_m(
    unsigned short* xh, unsigned short* xl, int xoff,
    const float* __restrict__ rel, const int* __restrict__ idx,
    const int* __restrict__ acode,
    const unsigned short* __restrict__ convh, const unsigned short* __restrict__ convl,
    const unsigned short* __restrict__ attnh, const unsigned short* __restrict__ attnl,
    const float* __restrict__ bng, const float* __restrict__ bnb,
    const float* __restrict__ ap, const float* __restrict__ as_, int ooff) {
  constexpr int K_TOT = L1M ? CPREV : 2 * CPREV;
  constexpr int NCH = K_TOT / 64;
  constexpr int KB = K_TOT / 32;
  constexpr int NT = FOUT / 16;
  constexpr int NT_W = NT / 4;          // conv n-tiles per wave (2x4 wave grid)
  constexpr int NTW_A = NT / 2;         // attn n-tiles per wave (head x half)
  constexpr int JW = (NTW_A > 2) ? 2 : NTW_A;   // small acc tile: no spill at 128 cap
  constexpr int NPASS = NTW_A / JW;
  constexpr int KBA = FOUT / 32;
  constexpr int YPLANE = 64 * FOUT * 2;  // bytes per y plane (frag-major)
  constexpr int S_BYTES = (2 * YPLANE > 16384) ? 2 * YPLANE : 16384;

  __shared__ alignas(16) char s_mem[S_BYTES];  // union: x-stage (16KB) / y (hi|lo)
  __shared__ int s_gsrc[64];
  __shared__ int s_code[64];

  int tid = threadIdx.x;
  int lane = tid & 63;
  int w = tid >> 6;
  int lg = lane >> 4;
  int ln = lane & 15;
  int pgbase = blockIdx.x * 4;

  if (tid < 64) {
    int pg = pgbase + (tid >> 4);
    int b = pg >> 11;
    s_gsrc[tid] = b * 2048 + idx[pg * KK + (tid & 15)];
    s_code[tid] = acode[pg * KK + (tid & 15)];
  }
  __syncthreads();

  // staging geometry: thread -> (row sr, 8-col group sq); frag-major dest:
  // mt=sr>>4, kb=sq>>2, l=(sq&3)*16+(sr&15) -> 16B contiguous per thread.
  int sr = tid >> 3;
  int sq = tid & 7;
  int wbyF = (((sr >> 4) * 2 + (sq >> 2)) * 64 + (sq & 3) * 16 + (sr & 15)) * 16;

  // conv wave roles: 2 row-halves x 4 col-quarters
  int wr = w >> 2, wc = w & 3;
  f32x4 cacc[2][NT_W];
#pragma unroll
  for (int m = 0; m < 2; ++m)
#pragma unroll
    for (int j = 0; j < NT_W; ++j) cacc[m][j] = (f32x4){0.f, 0.f, 0.f, 0.f};

  auto compute_chunk = [&](int ch) {
#pragma unroll
    for (int ks = 0; ks < 2; ++ks) {
      s16x8 ah[2], al[2];
#pragma unroll
      for (int m = 0; m < 2; ++m) {
        int by = (((wr * 2 + m) * 2 + ks) * 64 + lane) * 16;
        ah[m] = *(const s16x8*)(s_mem + by);
        al[m] = *(const s16x8*)(s_mem + 8192 + by);
      }
      int kb = ch * 2 + ks;
      __builtin_amdgcn_s_setprio(1);
#pragma unroll
      for (int j = 0; j < NT_W; ++j) {
        size_t fo = ((size_t)(wc * NT_W + j) * KB + kb) * 64 + lane;
        s16x8 bh = ((const s16x8*)convh)[fo];
        s16x8 bl = ((const s16x8*)convl)[fo];
#pragma unroll
        for (int m = 0; m < 2; ++m) {
          cacc[m][j] = mfma16(ah[m], bh, cacc[m][j]);
          cacc[m][j] = mfma16(al[m], bh, cacc[m][j]);
          cacc[m][j] = mfma16(ah[m], bl, cacc[m][j]);
        }
      }
      __builtin_amdgcn_s_setprio(0);
    }
  };

  if constexpr (L1M) {
    // compute PE in-place, single chunk
    float rc = rel[((size_t)(pgbase + (sr >> 4)) * KK + (sr & 15)) * 2 + (sq >> 2)];
    bool isSin = (sq & 3) < 2;
    unsigned short hb[8], lb[8];
#pragma unroll
    for (int i = 0; i < 8; ++i) {
      int j = (sq & 3) * 8 + i;
      int fidx = j & 15;
      float freq = exp2f(-(float)fidx * 0.8304820237218406f);  // 10000^(-fidx/16)
      float ang = rc * freq;
      float v = isSin ? __sinf(ang) : __cosf(ang);
      unsigned short hi = bfh(v);
      hb[i] = hi;
      lb[i] = bfh(v - bff(hi));
    }
    *(u16x8*)(s_mem + wbyF) = *(u16x8*)hb;
    *(u16x8*)(s_mem + 8192 + wbyF) = *(u16x8*)lb;
    __syncthreads();
    compute_chunk(0);
    __syncthreads();
  } else {
    const unsigned short* gAh = xh + (size_t)s_gsrc[sr] * 2048 + xoff + sq * 8;
    const unsigned short* gAl = xl + (size_t)s_gsrc[sr] * 2048 + xoff + sq * 8;
    const unsigned short* gCh = xh + (size_t)(pgbase + (sr >> 4)) * 2048 + xoff + sq * 8;
    const unsigned short* gCl = xl + (size_t)(pgbase + (sr >> 4)) * 2048 + xoff + sq * 8;
    auto srcp = [&](int ch, int plane) -> const unsigned short* {
      int c0 = ch * 64;
      bool aug = c0 >= CPREV;
      int coff = aug ? c0 - CPREV : c0;
      const unsigned short* p = plane ? (aug ? gCl : gAl) : (aug ? gCh : gAh);
      return p + coff;
    };
    u16x8 hv = *(const u16x8*)srcp(0, 0);
    u16x8 lv = *(const u16x8*)srcp(0, 1);
    for (int ch = 0; ch < NCH; ++ch) {
      *(u16x8*)(s_mem + wbyF) = hv;
      *(u16x8*)(s_mem + 8192 + wbyF) = lv;
      __syncthreads();
      if (ch + 1 < NCH) {  // prefetch: loads overlap this chunk's MFMA
        hv = *(const u16x8*)srcp(ch + 1, 0);
        lv = *(const u16x8*)srcp(ch + 1, 1);
      }
      compute_chunk(ch);
      __syncthreads();
    }
  }

  // conv epilogue: BN + leaky -> y (frag-major, overlays x buffer)
#pragma unroll
  for (int j = 0; j < NT_W; ++j) {
    int g = (wc * NT_W + j) * 16 + ln;
    float sc = bng[g] * INVS;
    float bs = bnb[g];
    int gpart = ((g >> 5) * 64 + ((g >> 3) & 3) * 16) * 16 + (g & 7) * 2;
#pragma unroll
    for (int m = 0; m < 2; ++m) {
#pragma unroll
      for (int reg = 0; reg < 4; ++reg) {
        int r = wr * 32 + m * 16 + lg * 4 + reg;
        float v = cacc[m][j][reg] * sc + bs;
        v = (v >= 0.f) ? v : NEGS * v;
        unsigned short hi = bfh(v);
        unsigned short lo = bfh(v - bff(hi));
        int by = (r >> 4) * (KBA * 1024) + gpart + (r & 15) * 16;
        *(unsigned short*)(s_mem + by) = hi;
        *(unsigned short*)(s_mem + YPLANE + by) = lo;
      }
    }
  }
  __syncthreads();

  // attention: wave = (head h, N-half nh)
  {
    int h = w >> 1, nh = w & 1;
    const s16x8* wph = (const s16x8*)(attnh + (size_t)h * FOUT * FOUT);
    const s16x8* wpl = (const s16x8*)(attnl + (size_t)h * FOUT * FOUT);
    const float* aph = ap + (size_t)h * PP * FOUT;
    const float* ash = as_ + (size_t)h * CC * FOUT;
    for (int pass = 0; pass < NPASS; ++pass) {
      f32x4 aacc[4][JW];
#pragma unroll
      for (int m = 0; m < 4; ++m)
#pragma unroll
        for (int j = 0; j < JW; ++j) aacc[m][j] = (f32x4){0.f, 0.f, 0.f, 0.f};
#pragma unroll 2
      for (int kb = 0; kb < KBA; ++kb) {
        s16x8 ah[4], al[4];
#pragma unroll
        for (int m = 0; m < 4; ++m) {
          int by = ((m * KBA + kb) * 64 + lane) * 16;
          ah[m] = *(const s16x8*)(s_mem + by);
          al[m] = *(const s16x8*)(s_mem + YPLANE + by);
        }
        __builtin_amdgcn_s_setprio(1);
#pragma unroll
        for (int j = 0; j < JW; ++j) {
          int nt = nh * NTW_A + pass * JW + j;
          size_t fo = ((size_t)nt * KBA + kb) * 64 + lane;
          s16x8 bh = wph[fo];
          s16x8 bl = wpl[fo];
#pragma unroll
          for (int m = 0; m < 4; ++m) {
            aacc[m][j] = mfma16(ah[m], bh, aacc[m][j]);
            aacc[m][j] = mfma16(al[m], bh, aacc[m][j]);
            aacc[m][j] = mfma16(ah[m], bl, aacc[m][j]);
          }
        }
        __builtin_amdgcn_s_setprio(0);
      }
#pragma unroll
      for (int m = 0; m < 4; ++m) {
        int pg = pgbase + m;
#pragma unroll
        for (int j = 0; j < JW; ++j) {
          int nt = nh * NTW_A + pass * JW + j;
          int g = nt * 16 + ln;
          float wv[4], e[4];
          float mx = -3.0e38f;
#pragma unroll
          for (int reg = 0; reg < 4; ++reg) {
            int code = s_code[m * 16 + lg * 4 + reg];
            const float* tb = (code < PP) ? (aph + (size_t)code * FOUT)
                                          : (ash + (size_t)(code - PP) * FOUT);
            float a = tb[g];
            float t = aacc[m][j][reg];
            wv[reg] = t;
            float ev = t * a;
            ev = (ev >= 0.f) ? ev : NEGS * ev;
            e[reg] = ev;
            mx = fmaxf(mx, ev);
          }
          mx = fmaxf(mx, __shfl_xor(mx, 16, 64));
          mx = fmaxf(mx, __shfl_xor(mx, 32, 64));
          float ssum = 0.f;
#pragma unroll
          for (int reg = 0; reg < 4; ++reg) {
            float pe = __expf(e[reg] - mx);
            e[reg] = pe;
            ssum += pe;
          }
          ssum += __shfl_xor(ssum, 16, 64);
          ssum += __shfl_xor(ssum, 32, 64);
          float inv = 1.f / ssum;
          float o = 0.f;
#pragma unroll
          for (int reg = 0; reg < 4; ++reg) {
            float u = e[reg] * inv * wv[reg];
            o += (u > 0.f) ? u : (__expf(u) - 1.f);
          }
          o += __shfl_xor(o, 16, 64);
          o += __shfl_xor(o, 32, 64);
          if (lane < 16) {
            size_t oc = (size_t)pg * 2048 + ooff + h * FOUT + g;
            unsigned short hi = bfh(o);
            xh[oc] = hi;
            xl[oc] = bfh(o - bff(hi));
          }
        }
      }
    }
  }
}

// ---------------------------------------------------------------- conv5 GEMM (MFMA, 8 waves)
// leaky(bn(X[4096][2048] @ B[2048][1024])), fused column max/sum partials per block.
// Frag-major s_a (conflict-free reads).
__global__ __launch_bounds__(512, 4) void k_gemm5_m(const unsigned short* __restrict__ xh,
                                                    const unsigned short* __restrict__ xl,
                                                    const unsigned short* __restrict__ bph,
                                                    const unsigned short* __restrict__ bpl,
                                                    const float* __restrict__ g5,
                                                    const float* __restrict__ b5,
                                                    float* __restrict__ pmax,
                                                    float* __restrict__ psum) {
  __shared__ alignas(16) char s_mem[32768];
  int tid = threadIdx.x;
  int lane = tid & 63;
  int w = tid >> 6;
  int lg = lane >> 4;
  int ln = lane & 15;
  int bm = blockIdx.x, bn = blockIdx.y;
  int wm = w >> 2, wn = w & 3;
  f32x4 acc[4][2];
#pragma unroll
  for (int m = 0; m < 4; ++m)
#pragma unroll
    for (int j = 0; j < 2; ++j) acc[m][j] = (f32x4){0.f, 0.f, 0.f, 0.f};

  int sr = tid >> 2;
  int sq = tid & 3;
  // frag-major dests for the two 8-col halves this thread stages
  int base0 = (((sr >> 4) * 2 + (sq >> 1)) * 64 + ((2 * sq) & 3) * 16 + (sr & 15)) * 16;
  int base1 = (((sr >> 4) * 2 + (sq >> 1)) * 64 + ((2 * sq + 1) & 3) * 16 + (sr & 15)) * 16;
  const unsigned short* gH = xh + (size_t)(bm * 128 + sr) * 2048 + sq * 16;
  const unsigned short* gL = xl + (size_t)(bm * 128 + sr) * 2048 + sq * 16;
  u16x8 h0 = *(const u16x8*)(gH);
  u16x8 h1 = *(const u16x8*)(gH + 8);
  u16x8 l0 = *(const u16x8*)(gL);
  u16x8 l1 = *(const u16x8*)(gL + 8);

  for (int ch = 0; ch < 32; ++ch) {
    *(u16x8*)(s_mem + base0) = h0;
    *(u16x8*)(s_mem + base1) = h1;
    *(u16x8*)(s_mem + 16384 + base0) = l0;
    *(u16x8*)(s_mem + 16384 + base1) = l1;
    __syncthreads();
    if (ch + 1 < 32) {
      h0 = *(const u16x8*)(gH + (ch + 1) * 64);
      h1 = *(const u16x8*)(gH + (ch + 1) * 64 + 8);
      l0 = *(const u16x8*)(gL + (ch + 1) * 64);
      l1 = *(const u16x8*)(gL + (ch + 1) * 64 + 8);
    }
#pragma unroll
    for (int ks = 0; ks < 2; ++ks) {
      s16x8 ah[4], al[4];
#pragma unroll
      for (int m = 0; m < 4; ++m) {
        int by = (((wm * 4 + m) * 2 + ks) * 64 + lane) * 16;
        ah[m] = *(const s16x8*)(s_mem + by);
        al[m] = *(const s16x8*)(s_mem + 16384 + by);
      }
      int kb = ch * 2 + ks;
      __builtin_amdgcn_s_setprio(1);
#pragma unroll
      for (int j = 0; j < 2; ++j) {
        size_t fo = ((size_t)(bn * 8 + wn * 2 + j) * 64 + kb) * 64 + lane;
        s16x8 bh = ((const s16x8*)bph)[fo];
        s16x8 bl = ((const s16x8*)bpl)[fo];
#pragma unroll
        for (int m = 0; m < 4; ++m) {
          acc[m][j] = mfma16(ah[m], bh, acc[m][j]);
          acc[m][j] = mfma16(al[m], bh, acc[m][j]);
          acc[m][j] = mfma16(ah[m], bl, acc[m][j]);
        }
      }
      __builtin_amdgcn_s_setprio(0);
    }
    __syncthreads();
  }

  // epilogue: BN + leaky, per-column (over this block's 128 rows) max & sum
  float cmax[2], csum[2];
#pragma unroll
  for (int j = 0; j < 2; ++j) {
    int g = bn * 128 + wn * 32 + j * 16 + ln;
    float sc = g5[g] * INVS;
    float bs = b5[g];
    float mx = -3.0e38f, sm = 0.f;
#pragma unroll
    for (int m = 0; m < 4; ++m)
#pragma unroll
      for (int reg = 0; reg < 4; ++reg) {
        float v = acc[m][j][reg] * sc + bs;
        v = (v >= 0.f) ? v : NEGS * v;
        mx = fmaxf(mx, v);
        sm += v;
      }
    mx = fmaxf(mx, __shfl_xor(mx, 16, 64));
    mx = fmaxf(mx, __shfl_xor(mx, 32, 64));
    sm += __shfl_xor(sm, 16, 64);
    sm += __shfl_xor(sm, 32, 64);
    cmax[j] = mx;
    csum[j] = sm;
  }
  float* s_f = (float*)s_mem;  // [2 wm][128 col][2]
  if (lg == 0) {
#pragma unroll
    for (int j = 0; j < 2; ++j) {
      int col = wn * 32 + j * 16 + ln;
      s_f[(wm * 128 + col) * 2 + 0] = cmax[j];
      s_f[(wm * 128 + col) * 2 + 1] = csum[j];
    }
  }
  __syncthreads();
  if (tid < 128) {
    float mx = fmaxf(s_f[tid * 2], s_f[(128 + tid) * 2]);
    float sm = s_f[tid * 2 + 1] + s_f[(128 + tid) * 2 + 1];
    pmax[(size_t)bm * 1024 + bn * 128 + tid] = mx;
    psum[(size_t)bm * 1024 + bn * 128 + tid] = sm;
  }
}

// ---------------------------------------------------------------- feat + head
__global__ __launch_bounds__(256) void k_feat(const float* __restrict__ pmax,
                                              const float* __restrict__ psum,
                                              float* __restrict__ feat) {
  int t = blockIdx.x * 256 + threadIdx.x;
  if (t >= BB * 1024) return;
  int b = t >> 10, o = t & 1023;
  float mx = -3.0e38f, sm = 0.f;
  for (int i = 0; i < 16; ++i) {
    mx = fmaxf(mx, pmax[(size_t)(b * 16 + i) * 1024 + o]);
    sm += psum[(size_t)(b * 16 + i) * 1024 + o];
  }
  feat[b * 2048 + o] = mx;
  feat[b * 2048 + 1024 + o] = sm * (1.0f / NN);
}

template <bool HASB, bool DOBN, bool ACT>
__global__ __launch_bounds__(256) void k_head(const float* __restrict__ X,
                                              const float* __restrict__ Wm,
                                              const float* __restrict__ bias,
                                              const float* __restrict__ g,
                                              const float* __restrict__ bb,
                                              float* __restrict__ Y, int IN, int ON) {
  int gt = blockIdx.x * 256 + threadIdx.x;
  int w = gt >> 6, lane = gt & 63;
  if (w >= BB * ON) return;
  int b = w / ON, o = w - b * ON;
  const float* x = X + (size_t)b * IN;
  const float* wr = Wm + (size_t)o * IN;
  float s = 0.f;
  for (int c = lane; c < IN; c += 64) s += x[c] * wr[c];
#pragma unroll
  for (int off = 32; off > 0; off >>= 1) s += __shfl_down(s, off, 64);
  if (lane == 0) {
    if (HASB) s += bias[o];
    if (DOBN) s = s * INVS * g[o] + bb[o];
    if (ACT) s = (s >= 0.f) ? s : NEGS * s;
    Y[(size_t)b * ON + o] = s;
  }
}

// ---------------------------------------------------------------- launch
extern "C" void kernel_launch(void* const* d_in, const int* in_sizes, int n_in,
                              void* d_out, int out_size, void* d_ws, size_t ws_size,
                              hipStream_t stream) {
  const float* pos = (const float*)d_in[0];
  const int* types = (const int*)d_in[1];
  const float* conv1_w = (const float*)d_in[2];
  const float* bn1_g = (const float*)d_in[3];
  const float* bn1_b = (const float*)d_in[4];
  const float* W1 = (const float*)d_in[5];
  const float* ap1 = (const float*)d_in[6];
  const float* as1 = (const float*)d_in[7];
  const float* conv2_w = (const float*)d_in[8];
  const float* bn2_g = (const float*)d_in[9];
  const float* bn2_b = (const float*)d_in[10];
  const float* W2 = (const float*)d_in[11];
  const float* ap2 = (const float*)d_in[12];
  const float* as2 = (const float*)d_in[13];
  const float* conv3_w = (const float*)d_in[14];
  const float* bn3_g = (const float*)d_in[15];
  const float* bn3_b = (const float*)d_in[16];
  const float* W3 = (const float*)d_in[17];
  const float* ap3 = (const float*)d_in[18];
  const float* as3 = (const float*)d_in[19];
  const float* conv4_w = (const float*)d_in[20];
  const float* bn4_g = (const float*)d_in[21];
  const float* bn4_b = (const float*)d_in[22];
  const float* W4 = (const float*)d_in[23];
  const float* ap4 = (const float*)d_in[24];
  const float* as4 = (const float*)d_in[25];
  const float* conv5_w = (const float*)d_in[26];
  const float* bn5_g = (const float*)d_in[27];
  const float* bn5_b = (const float*)d_in[28];
  const float* lin1_w = (const float*)d_in[29];
  const float* bn6_g = (const float*)d_in[30];
  const float* bn6_b = (const float*)d_in[31];
  const float* lin2_w = (const float*)d_in[32];
  const float* lin2_b = (const float*)d_in[33];
  const float* bn7_g = (const float*)d_in[34];
  const float* bn7_b = (const float*)d_in[35];
  const float* lin3_w = (const float*)d_in[36];
  const float* lin3_b = (const float*)d_in[37];
  (void)in_sizes; (void)n_in; (void)out_size; (void)ws_size;

  float* ws = (float*)d_ws;
  size_t off = 0;
  auto take = [&](size_t nf) {
    float* p = ws + off;
    off += (nf + 63) & ~(size_t)63;
    return p;
  };
  auto takeu = [&](size_t nu) { return (unsigned short*)take((nu + 1) / 2); };

  int* idx = (int*)take(BB * NN * KK);
  int* acode = (int*)take(BB * NN * KK);
  float* rel = take((size_t)BB * NN * KK * 2);
  unsigned short* xh = takeu((size_t)BB * NN * 2048);
  unsigned short* xl = takeu((size_t)BB * NN * 2048);
  float* pmax = take(32 * 1024);
  float* psum = take(32 * 1024);
  float* feat = take(BB * 2048);
  float* h1 = take(BB * 512);
  float* h2 = take(BB * 256);
  unsigned short* c1h = takeu(64 * 64);
  unsigned short* c1l = takeu(64 * 64);
  unsigned short* c2h = takeu(512 * 64);
  unsigned short* c2l = takeu(512 * 64);
  unsigned short* c3h = takeu(512 * 128);
  unsigned short* c3l = takeu(512 * 128);
  unsigned short* c4h = takeu(1024 * 256);
  unsigned short* c4l = takeu(1024 * 256);
  unsigned short* a1h = takeu(4 * 64 * 64);
  unsigned short* a1l = takeu(4 * 64 * 64);
  unsigned short* a2h = takeu(4 * 64 * 64);
  unsigned short* a2l = takeu(4 * 64 * 64);
  unsigned short* a3h = takeu(4 * 128 * 128);
  unsigned short* a3l = takeu(4 * 128 * 128);
  unsigned short* a4h = takeu(4 * 256 * 256);
  unsigned short* a4l = takeu(4 * 256 * 256);
  unsigned short* g5h = takeu((size_t)2048 * 1024);
  unsigned short* g5l = takeu((size_t)2048 * 1024);

  dim3 blk(256);
  dim3 blk5(512);
  k_pack<<<dim3(2, 1), blk, 0, stream>>>(conv1_w, c1h, c1l, 2, 4, 64, 0, 1, 0, 0);
  k_pack<<<dim3(16, 1), blk, 0, stream>>>(conv2_w, c2h, c2l, 16, 4, 512, 256, 1, 0, 0);
  k_pack<<<dim3(32, 1), blk, 0, stream>>>(conv3_w, c3h, c3l, 16, 8, 512, 256, 1, 0, 0);
  k_pack<<<dim3(128, 1), blk, 0, stream>>>(conv4_w, c4h, c4l, 32, 16, 1024, 512, 1, 0, 0);
  k_pack<<<dim3(2, 4), blk, 0, stream>>>(W1, a1h, a1l, 2, 4, 64, 0, 0, 64 * 64, 64 * 64);
  k_pack<<<dim3(2, 4), blk, 0, stream>>>(W2, a2h, a2l, 2, 4, 64, 0, 0, 64 * 64, 64 * 64);
  k_pack<<<dim3(8, 4), blk, 0, stream>>>(W3, a3h, a3l, 4, 8, 128, 0, 0, 128 * 128, 128 * 128);
  k_pack<<<dim3(32, 4), blk, 0, stream>>>(W4, a4h, a4l, 8, 16, 256, 0, 0, 256 * 256, 256 * 256);
  k_pack<<<dim3(1024, 1), blk, 0, stream>>>(conv5_w, g5h, g5l, 64, 64, 2048, 0, 1, 0, 0);

  k_ballquery<<<dim3(BB * NN / 4), blk, 0, stream>>>(pos, types, idx, acode, rel);

  k_layer_m<64, 64, true><<<dim3(BB * NN / 4), blk5, 0, stream>>>(
      xh, xl, 0, rel, idx, acode, c1h, c1l, a1h, a1l, bn1_g, bn1_b, ap1, as1, 0);
  k_layer_m<256, 64, false><<<dim3(BB * NN / 4), blk5, 0, stream>>>(
      xh, xl, 0, rel, idx, acode, c2h, c2l, a2h, a2l, bn2_g, bn2_b, ap2, as2, 256);
  k_layer_m<256, 128, false><<<dim3(BB * NN / 4), blk5, 0, stream>>>(
      xh, xl, 256, rel, idx, acode, c3h, c3l, a3h, a3l, bn3_g, bn3_b, ap3, as3, 512);
  k_layer_m<512, 256, false><<<dim3(BB * NN / 4), blk5, 0, stream>>>(
      xh, xl, 512, rel, idx, acode, c4h, c4l, a4h, a4l, bn4_g, bn4_b, ap4, as4, 1024);

  k_gemm5_m<<<dim3(32, 8), blk5, 0, stream>>>(xh, xl, g5h, g5l, bn5_g, bn5_b, pmax, psum);
  k_feat<<<dim3(8), blk, 0, stream>>>(pmax, psum, feat);
  k_head<false, true, true><<<dim3(BB * 512 * 64 / 256), blk, 0, stream>>>(
      feat, lin1_w, nullptr, bn6_g, bn6_b, h1, 2048, 512);
  k_head<true, true, true><<<dim3(BB * 256 * 64 / 256), blk, 0, stream>>>(
      h1, lin2_w, lin2_b, bn7_g, bn7_b, h2, 512, 256);
  k_head<true, false, false><<<dim3(1), blk, 0, stream>>>(
      h2, lin3_w, lin3_b, nullptr, nullptr, (float*)d_out, 256, 2);
}

// Round 6
// 530.478 us; speedup vs baseline: 3.8390x; 1.0276x over previous
//
#include <hip/hip_runtime.h>
#include <math.h>

#define BB 2
#define NN 2048
#define KK 16
#define HH 4
#define CC 8
#define PP 36
#define NEGS 0.2f
#define INVS 0.9999950000374997f  // 1/sqrt(1+1e-5)

typedef __attribute__((ext_vector_type(8))) short s16x8;
typedef __attribute__((ext_vector_type(8))) unsigned short u16x8;
typedef __attribute__((ext_vector_type(4))) float f32x4;

__device__ inline unsigned short bfh(float x) {
  unsigned u = __float_as_uint(x);
  return (unsigned short)((u + 0x7FFFu + ((u >> 16) & 1u)) >> 16);
}
__device__ inline float bff(unsigned short h) {
  return __uint_as_float(((unsigned)h) << 16);
}
__device__ inline f32x4 mfma16(s16x8 a, s16x8 b, f32x4 c) {
  return __builtin_amdgcn_mfma_f32_16x16x32_bf16(a, b, c, 0, 0, 0);
}

// ---------------------------------------------------------------- ball query
__global__ __launch_bounds__(256) void k_ballquery(const float* __restrict__ pos,
                                                   const int* __restrict__ types,
                                                   int* __restrict__ idxg,
                                                   int* __restrict__ acode,
                                                   float* __restrict__ rel) {
  __shared__ int s_buf[4][KK];
  const float r2 = (float)(0.08 * 0.08);
  int wslot = threadIdx.x >> 6;
  int lane = threadIdx.x & 63;
  int wg = blockIdx.x * 4 + wslot;
  int b = wg / NN, n = wg - b * NN;
  const float* pb = pos + (size_t)b * NN * 2;
  float px = pb[n * 2 + 0], py = pb[n * 2 + 1];
  float sqn = px * px + py * py;
  unsigned mask = 0u;
  int base = lane * 32;
  for (int j = 0; j < 32; ++j) {
    float qx = pb[(base + j) * 2 + 0], qy = pb[(base + j) * 2 + 1];
    float sqm = qx * qx + qy * qy;
    float d = sqn + sqm - 2.0f * (px * qx + py * qy);
    if (d <= r2) mask |= (1u << j);
  }
  int cnt = __popc(mask);
  int inc = cnt;
#pragma unroll
  for (int off = 1; off < 64; off <<= 1) {
    int v = __shfl_up(inc, off, 64);
    if (lane >= off) inc += v;
  }
  int total = __shfl(inc, 63, 64);
  int excl = inc - cnt;
  unsigned mm = mask;
  int p = excl;
  while (mm && p < KK) {
    int j = __ffs(mm) - 1;
    mm &= mm - 1u;
    s_buf[wslot][p] = base + j;
    ++p;
  }
  __syncthreads();
  int tc = total < KK ? total : KK;
  if (lane < KK) {
    int m0 = s_buf[wslot][0];
    int mk = (lane < tc) ? s_buf[wslot][lane] : m0;
    idxg[wg * KK + lane] = mk;
    int core = types[b * NN + n];
    int tg = types[b * NN + mk];
    int s0 = tg < core ? tg : core;
    int s1 = tg < core ? core : tg;
    int code = s0 * CC - (s0 * (s0 - 1)) / 2 + (s1 - s0);
    if (lane == 0 && tg < core) code = PP + core;
    acode[wg * KK + lane] = code;
    rel[(wg * KK + lane) * 2 + 0] = pb[mk * 2 + 0] - px;
    rel[(wg * KK + lane) * 2 + 1] = pb[mk * 2 + 1] - py;
  }
}

// ---------------------------------------------------------------- weight pack
// frag layout: elem(kb,nt,l,i) = B[kb*32 + (l>>4)*8 + i][nt*16 + (l&15)]
__global__ __launch_bounds__(256) void k_pack(const float* __restrict__ src,
                                              unsigned short* __restrict__ dh,
                                              unsigned short* __restrict__ dl,
                                              int KB, int NT, int srcld, int Cdiff,
                                              int mode, int sstride, int dstride) {
  src += (size_t)blockIdx.y * sstride;
  dh += (size_t)blockIdx.y * dstride;
  dl += (size_t)blockIdx.y * dstride;
  int f = blockIdx.x * 256 + threadIdx.x;
  int total = KB * NT * 64;
  if (f >= total) return;
  int l = f & 63;
  int t2 = f >> 6;
  int n = (t2 / KB) * 16 + (l & 15);
  int k0 = (t2 % KB) * 32 + ((l >> 4) * 8);
  size_t o = (size_t)t2 * 512 + (size_t)l * 8;
#pragma unroll
  for (int i = 0; i < 8; ++i) {
    int k = k0 + i;
    float v;
    if (mode == 0) {
      v = src[(size_t)k * srcld + n];
    } else {
      v = src[(size_t)n * srcld + k];
      if (Cdiff > 0 && k >= Cdiff) v -= src[(size_t)n * srcld + k - Cdiff];
    }
    unsigned short hi = bfh(v);
    dh[o + i] = hi;
    dl[o + i] = bfh(v - bff(hi));
  }
}

// ---------------------------------------------------------------- fused layer (MFMA, 8 waves)
// Block = 4 points (64 neighbor rows), 512 threads, 2 blocks/CU.
// Conv staging is WAVE-OWNS-FRAG: wave w stages fragment w (mt=w>>1,kb=w&1), lane l
// loads frag element l from global and writes contiguous 16B -> conflict-free LDS
// writes (R5's (sr,sq) map was an 8-way write conflict). x-chunk is double-buffered
// (16KB x 2, unioned with y): one barrier per chunk, loads overlap MFMA.
template <int CPREV, int FOUT, bool L1M>
__global__ __launch_bounds__(512, 4) void k_layer_m(
    unsigned short* xh, unsigned short* xl, int xoff,
    const float* __restrict__ rel, const int* __restrict__ idx,
    const int* __restrict__ acode,
    const unsigned short* __restrict__ convh, const unsigned short* __restrict__ convl,
    const unsigned short* __restrict__ attnh, const unsigned short* __restrict__ attnl,
    const float* __restrict__ bng, const float* __restrict__ bnb,
    const float* __restrict__ ap, const float* __restrict__ as_, int ooff) {
  constexpr int K_TOT = L1M ? CPREV : 2 * CPREV;
  constexpr int NCH = K_TOT / 64;
  constexpr int KB = K_TOT / 32;
  constexpr int NT = FOUT / 16;
  constexpr int NT_W = NT / 4;          // conv n-tiles per wave (2x4 wave grid)
  constexpr int NTW_A = NT / 2;         // attn n-tiles per wave (head x half)
  constexpr int JW = (NTW_A > 2) ? 2 : NTW_A;   // small acc tile: no spill at 128 cap
  constexpr int NPASS = NTW_A / JW;
  constexpr int KBA = FOUT / 32;
  constexpr int YPLANE = 64 * FOUT * 2;  // bytes per y plane (frag-major)
  constexpr int S_BYTES = (2 * YPLANE > 32768) ? 2 * YPLANE : 32768;

  __shared__ alignas(16) char s_mem[S_BYTES];  // union: x dbuf (2x16KB) / y (hi|lo)
  __shared__ int s_gsrc[64];
  __shared__ int s_code[64];

  int tid = threadIdx.x;
  int lane = tid & 63;
  int w = tid >> 6;
  int lg = lane >> 4;
  int ln = lane & 15;
  int pgbase = blockIdx.x * 4;

  if (tid < 64) {
    int pg = pgbase + (tid >> 4);
    int b = pg >> 11;
    s_gsrc[tid] = b * 2048 + idx[pg * KK + (tid & 15)];
    s_code[tid] = acode[pg * KK + (tid & 15)];
  }
  __syncthreads();

  // wave-owns-frag staging geometry
  int smt = w >> 1, skb = w & 1;
  int wby0 = (w * 64 + lane) * 16;  // dest within a buffer's hi plane

  // conv wave roles: 2 row-halves x 4 col-quarters
  int wr = w >> 2, wc = w & 3;
  f32x4 cacc[2][NT_W];
#pragma unroll
  for (int m = 0; m < 2; ++m)
#pragma unroll
    for (int j = 0; j < NT_W; ++j) cacc[m][j] = (f32x4){0.f, 0.f, 0.f, 0.f};

  auto compute_chunk = [&](int ch, int p) {
#pragma unroll
    for (int ks = 0; ks < 2; ++ks) {
      s16x8 ah[2], al[2];
#pragma unroll
      for (int m = 0; m < 2; ++m) {
        int by = p * 16384 + (((wr * 2 + m) * 2 + ks) * 64 + lane) * 16;
        ah[m] = *(const s16x8*)(s_mem + by);
        al[m] = *(const s16x8*)(s_mem + by + 8192);
      }
      int kb = ch * 2 + ks;
      __builtin_amdgcn_s_setprio(1);
#pragma unroll
      for (int j = 0; j < NT_W; ++j) {
        size_t fo = ((size_t)(wc * NT_W + j) * KB + kb) * 64 + lane;
        s16x8 bh = ((const s16x8*)convh)[fo];
        s16x8 bl = ((const s16x8*)convl)[fo];
#pragma unroll
        for (int m = 0; m < 2; ++m) {
          cacc[m][j] = mfma16(ah[m], bh, cacc[m][j]);
          cacc[m][j] = mfma16(al[m], bh, cacc[m][j]);
          cacc[m][j] = mfma16(ah[m], bl, cacc[m][j]);
        }
      }
      __builtin_amdgcn_s_setprio(0);
    }
  };

  if constexpr (L1M) {
    // compute PE directly into frag w: lane l -> row smt*16+ln, col skb*32+lg*8+i
    float rc = rel[((size_t)(pgbase + smt) * KK + ln) * 2 + skb];
    unsigned short hb[8], lb[8];
#pragma unroll
    for (int i = 0; i < 8; ++i) {
      int j = lg * 8 + i;  // col & 31
      int fidx = j & 15;
      float freq = exp2f(-(float)fidx * 0.8304820237218406f);  // 10000^(-fidx/16)
      float ang = rc * freq;
      float v = (j < 16) ? __sinf(ang) : __cosf(ang);
      unsigned short hi = bfh(v);
      hb[i] = hi;
      lb[i] = bfh(v - bff(hi));
    }
    *(u16x8*)(s_mem + wby0) = *(u16x8*)hb;
    *(u16x8*)(s_mem + wby0 + 8192) = *(u16x8*)lb;
    __syncthreads();
    compute_chunk(0, 0);
    __syncthreads();
  } else {
    int srow = smt * 16 + ln;
    int colb = skb * 32 + lg * 8;
    int gsrcRow = s_gsrc[srow];
    int crow = pgbase + smt;
    auto loadpair = [&](int ch, u16x8& h, u16x8& l) {
      int c = ch * 64 + colb;
      bool aug = (ch * 64 + skb * 32) >= CPREV;  // wave-uniform
      int grow = aug ? crow : gsrcRow;
      int cc = xoff + (aug ? c - CPREV : c);
      h = *(const u16x8*)(xh + (size_t)grow * 2048 + cc);
      l = *(const u16x8*)(xl + (size_t)grow * 2048 + cc);
    };
    u16x8 hv, lv;
    loadpair(0, hv, lv);
    *(u16x8*)(s_mem + wby0) = hv;
    *(u16x8*)(s_mem + wby0 + 8192) = lv;
    __syncthreads();
    int p = 0;
    for (int ch = 0; ch < NCH; ++ch) {
      if (ch + 1 < NCH) loadpair(ch + 1, hv, lv);  // issue before MFMA
      compute_chunk(ch, p);
      if (ch + 1 < NCH) {
        int d = (p ^ 1) * 16384 + wby0;
        *(u16x8*)(s_mem + d) = hv;
        *(u16x8*)(s_mem + d + 8192) = lv;
        p ^= 1;
      }
      __syncthreads();
    }
  }

  // conv epilogue: BN + leaky -> y (frag-major, overlays x buffers)
#pragma unroll
  for (int j = 0; j < NT_W; ++j) {
    int g = (wc * NT_W + j) * 16 + ln;
    float sc = bng[g] * INVS;
    float bs = bnb[g];
    int gpart = ((g >> 5) * 64 + ((g >> 3) & 3) * 16) * 16 + (g & 7) * 2;
#pragma unroll
    for (int m = 0; m < 2; ++m) {
#pragma unroll
      for (int reg = 0; reg < 4; ++reg) {
        int r = wr * 32 + m * 16 + lg * 4 + reg;
        float v = cacc[m][j][reg] * sc + bs;
        v = (v >= 0.f) ? v : NEGS * v;
        unsigned short hi = bfh(v);
        unsigned short lo = bfh(v - bff(hi));
        int by = (r >> 4) * (KBA * 1024) + gpart + (r & 15) * 16;
        *(unsigned short*)(s_mem + by) = hi;
        *(unsigned short*)(s_mem + YPLANE + by) = lo;
      }
    }
  }
  __syncthreads();

  // attention: wave = (head h, N-half nh)
  {
    int h = w >> 1, nh = w & 1;
    const s16x8* wph = (const s16x8*)(attnh + (size_t)h * FOUT * FOUT);
    const s16x8* wpl = (const s16x8*)(attnl + (size_t)h * FOUT * FOUT);
    const float* aph = ap + (size_t)h * PP * FOUT;
    const float* ash = as_ + (size_t)h * CC * FOUT;
    for (int pass = 0; pass < NPASS; ++pass) {
      f32x4 aacc[4][JW];
#pragma unroll
      for (int m = 0; m < 4; ++m)
#pragma unroll
        for (int j = 0; j < JW; ++j) aacc[m][j] = (f32x4){0.f, 0.f, 0.f, 0.f};
#pragma unroll 2
      for (int kb = 0; kb < KBA; ++kb) {
        s16x8 ah[4], al[4];
#pragma unroll
        for (int m = 0; m < 4; ++m) {
          int by = ((m * KBA + kb) * 64 + lane) * 16;
          ah[m] = *(const s16x8*)(s_mem + by);
          al[m] = *(const s16x8*)(s_mem + YPLANE + by);
        }
        __builtin_amdgcn_s_setprio(1);
#pragma unroll
        for (int j = 0; j < JW; ++j) {
          int nt = nh * NTW_A + pass * JW + j;
          size_t fo = ((size_t)nt * KBA + kb) * 64 + lane;
          s16x8 bh = wph[fo];
          s16x8 bl = wpl[fo];
#pragma unroll
          for (int m = 0; m < 4; ++m) {
            aacc[m][j] = mfma16(ah[m], bh, aacc[m][j]);
            aacc[m][j] = mfma16(al[m], bh, aacc[m][j]);
            aacc[m][j] = mfma16(ah[m], bl, aacc[m][j]);
          }
        }
        __builtin_amdgcn_s_setprio(0);
      }
#pragma unroll
      for (int m = 0; m < 4; ++m) {
        int pg = pgbase + m;
#pragma unroll
        for (int j = 0; j < JW; ++j) {
          int nt = nh * NTW_A + pass * JW + j;
          int g = nt * 16 + ln;
          float wv[4], e[4];
          float mx = -3.0e38f;
#pragma unroll
          for (int reg = 0; reg < 4; ++reg) {
            int code = s_code[m * 16 + lg * 4 + reg];
            const float* tb = (code < PP) ? (aph + (size_t)code * FOUT)
                                          : (ash + (size_t)(code - PP) * FOUT);
            float a = tb[g];
            float t = aacc[m][j][reg];
            wv[reg] = t;
            float ev = t * a;
            ev = (ev >= 0.f) ? ev : NEGS * ev;
            e[reg] = ev;
            mx = fmaxf(mx, ev);
          }
          mx = fmaxf(mx, __shfl_xor(mx, 16, 64));
          mx = fmaxf(mx, __shfl_xor(mx, 32, 64));
          float ssum = 0.f;
#pragma unroll
          for (int reg = 0; reg < 4; ++reg) {
            float pe = __expf(e[reg] - mx);
            e[reg] = pe;
            ssum += pe;
          }
          ssum += __shfl_xor(ssum, 16, 64);
          ssum += __shfl_xor(ssum, 32, 64);
          float inv = 1.f / ssum;
          float o = 0.f;
#pragma unroll
          for (int reg = 0; reg < 4; ++reg) {
            float u = e[reg] * inv * wv[reg];
            o += (u > 0.f) ? u : (__expf(u) - 1.f);
          }
          o += __shfl_xor(o, 16, 64);
          o += __shfl_xor(o, 32, 64);
          if (lane < 16) {
            size_t oc = (size_t)pg * 2048 + ooff + h * FOUT + g;
            unsigned short hi = bfh(o);
            xh[oc] = hi;
            xl[oc] = bfh(o - bff(hi));
          }
        }
      }
    }
  }
}

// ---------------------------------------------------------------- conv5 GEMM (MFMA, 8 waves)
// leaky(bn(X[4096][2048] @ B[2048][1024])), fused column max/sum partials.
// Wave-owns-frag staging (conflict-free writes) + LDS double-buffer.
__global__ __launch_bounds__(512, 4) void k_gemm5_m(const unsigned short* __restrict__ xh,
                                                    const unsigned short* __restrict__ xl,
                                                    const unsigned short* __restrict__ bph,
                                                    const unsigned short* __restrict__ bpl,
                                                    const float* __restrict__ g5,
                                                    const float* __restrict__ b5,
                                                    float* __restrict__ pmax,
                                                    float* __restrict__ psum) {
  __shared__ alignas(16) char s_mem[65536];
  int tid = threadIdx.x;
  int lane = tid & 63;
  int w = tid >> 6;
  int lg = lane >> 4;
  int ln = lane & 15;
  int bm = blockIdx.x, bn = blockIdx.y;
  int wm = w >> 2, wn = w & 3;
  f32x4 acc[4][2];
#pragma unroll
  for (int m = 0; m < 4; ++m)
#pragma unroll
    for (int j = 0; j < 2; ++j) acc[m][j] = (f32x4){0.f, 0.f, 0.f, 0.f};

  // staging: wave w = m-tile w; lane l loads frag elements for kb=0,1
  int srowg = bm * 128 + w * 16 + ln;
  const unsigned short* gH = xh + (size_t)srowg * 2048 + lg * 8;
  const unsigned short* gL = xl + (size_t)srowg * 2048 + lg * 8;
  int wbyA = ((w * 2 + 0) * 64 + lane) * 16;
  int wbyB = ((w * 2 + 1) * 64 + lane) * 16;
  u16x8 h0, h1, l0, l1;
  auto load4 = [&](int ch) {
    h0 = *(const u16x8*)(gH + ch * 64);
    h1 = *(const u16x8*)(gH + ch * 64 + 32);
    l0 = *(const u16x8*)(gL + ch * 64);
    l1 = *(const u16x8*)(gL + ch * 64 + 32);
  };
  load4(0);
  *(u16x8*)(s_mem + wbyA) = h0;
  *(u16x8*)(s_mem + wbyB) = h1;
  *(u16x8*)(s_mem + wbyA + 16384) = l0;
  *(u16x8*)(s_mem + wbyB + 16384) = l1;
  __syncthreads();
  int p = 0;
  for (int ch = 0; ch < 32; ++ch) {
    if (ch + 1 < 32) load4(ch + 1);
#pragma unroll
    for (int ks = 0; ks < 2; ++ks) {
      s16x8 ah[4], al[4];
#pragma unroll
      for (int m = 0; m < 4; ++m) {
        int by = p * 32768 + (((wm * 4 + m) * 2 + ks) * 64 + lane) * 16;
        ah[m] = *(const s16x8*)(s_mem + by);
        al[m] = *(const s16x8*)(s_mem + by + 16384);
      }
      int kb = ch * 2 + ks;
      __builtin_amdgcn_s_setprio(1);
#pragma unroll
      for (int j = 0; j < 2; ++j) {
        size_t fo = ((size_t)(bn * 8 + wn * 2 + j) * 64 + kb) * 64 + lane;
        s16x8 bh = ((const s16x8*)bph)[fo];
        s16x8 bl = ((const s16x8*)bpl)[fo];
#pragma unroll
        for (int m = 0; m < 4; ++m) {
          acc[m][j] = mfma16(ah[m], bh, acc[m][j]);
          acc[m][j] = mfma16(al[m], bh, acc[m][j]);
          acc[m][j] = mfma16(ah[m], bl, acc[m][j]);
        }
      }
      __builtin_amdgcn_s_setprio(0);
    }
    if (ch + 1 < 32) {
      int d = (p ^ 1) * 32768;
      *(u16x8*)(s_mem + d + wbyA) = h0;
      *(u16x8*)(s_mem + d + wbyB) = h1;
      *(u16x8*)(s_mem + d + wbyA + 16384) = l0;
      *(u16x8*)(s_mem + d + wbyB + 16384) = l1;
      p ^= 1;
    }
    __syncthreads();
  }

  // epilogue: BN + leaky, per-column (over this block's 128 rows) max & sum
  float cmax[2], csum[2];
#pragma unroll
  for (int j = 0; j < 2; ++j) {
    int g = bn * 128 + wn * 32 + j * 16 + ln;
    float sc = g5[g] * INVS;
    float bs = b5[g];
    float mx = -3.0e38f, sm = 0.f;
#pragma unroll
    for (int m = 0; m < 4; ++m)
#pragma unroll
      for (int reg = 0; reg < 4; ++reg) {
        float v = acc[m][j][reg] * sc + bs;
        v = (v >= 0.f) ? v : NEGS * v;
        mx = fmaxf(mx, v);
        sm += v;
      }
    mx = fmaxf(mx, __shfl_xor(mx, 16, 64));
    mx = fmaxf(mx, __shfl_xor(mx, 32, 64));
    sm += __shfl_xor(sm, 16, 64);
    sm += __shfl_xor(sm, 32, 64);
    cmax[j] = mx;
    csum[j] = sm;
  }
  float* s_f = (float*)s_mem;  // [2 wm][128 col][2]
  if (lg == 0) {
#pragma unroll
    for (int j = 0; j < 2; ++j) {
      int col = wn * 32 + j * 16 + ln;
      s_f[(wm * 128 + col) * 2 + 0] = cmax[j];
      s_f[(wm * 128 + col) * 2 + 1] = csum[j];
    }
  }
  __syncthreads();
  if (tid < 128) {
    float mx = fmaxf(s_f[tid * 2], s_f[(128 + tid) * 2]);
    float sm = s_f[tid * 2 + 1] + s_f[(128 + tid) * 2 + 1];
    pmax[(size_t)bm * 1024 + bn * 128 + tid] = mx;
    psum[(size_t)bm * 1024 + bn * 128 + tid] = sm;
  }
}

// ---------------------------------------------------------------- feat + head
__global__ __launch_bounds__(256) void k_feat(const float* __restrict__ pmax,
                                              const float* __restrict__ psum,
                                              float* __restrict__ feat) {
  int t = blockIdx.x * 256 + threadIdx.x;
  if (t >= BB * 1024) return;
  int b = t >> 10, o = t & 1023;
  float mx = -3.0e38f, sm = 0.f;
  for (int i = 0; i < 16; ++i) {
    mx = fmaxf(mx, pmax[(size_t)(b * 16 + i) * 1024 + o]);
    sm += psum[(size_t)(b * 16 + i) * 1024 + o];
  }
  feat[b * 2048 + o] = mx;
  feat[b * 2048 + 1024 + o] = sm * (1.0f / NN);
}

template <bool HASB, bool DOBN, bool ACT>
__global__ __launch_bounds__(256) void k_head(const float* __restrict__ X,
                                              const float* __restrict__ Wm,
                                              const float* __restrict__ bias,
                                              const float* __restrict__ g,
                                              const float* __restrict__ bb,
                                              float* __restrict__ Y, int IN, int ON) {
  int gt = blockIdx.x * 256 + threadIdx.x;
  int w = gt >> 6, lane = gt & 63;
  if (w >= BB * ON) return;
  int b = w / ON, o = w - b * ON;
  const float* x = X + (size_t)b * IN;
  const float* wr = Wm + (size_t)o * IN;
  float s = 0.f;
  for (int c = lane; c < IN; c += 64) s += x[c] * wr[c];
#pragma unroll
  for (int off = 32; off > 0; off >>= 1) s += __shfl_down(s, off, 64);
  if (lane == 0) {
    if (HASB) s += bias[o];
    if (DOBN) s = s * INVS * g[o] + bb[o];
    if (ACT) s = (s >= 0.f) ? s : NEGS * s;
    Y[(size_t)b * ON + o] = s;
  }
}

// ---------------------------------------------------------------- launch
extern "C" void kernel_launch(void* const* d_in, const int* in_sizes, int n_in,
                              void* d_out, int out_size, void* d_ws, size_t ws_size,
                              hipStream_t stream) {
  const float* pos = (const float*)d_in[0];
  const int* types = (const int*)d_in[1];
  const float* conv1_w = (const float*)d_in[2];
  const float* bn1_g = (const float*)d_in[3];
  const float* bn1_b = (const float*)d_in[4];
  const float* W1 = (const float*)d_in[5];
  const float* ap1 = (const float*)d_in[6];
  const float* as1 = (const float*)d_in[7];
  const float* conv2_w = (const float*)d_in[8];
  const float* bn2_g = (const float*)d_in[9];
  const float* bn2_b = (const float*)d_in[10];
  const float* W2 = (const float*)d_in[11];
  const float* ap2 = (const float*)d_in[12];
  const float* as2 = (const float*)d_in[13];
  const float* conv3_w = (const float*)d_in[14];
  const float* bn3_g = (const float*)d_in[15];
  const float* bn3_b = (const float*)d_in[16];
  const float* W3 = (const float*)d_in[17];
  const float* ap3 = (const float*)d_in[18];
  const float* as3 = (const float*)d_in[19];
  const float* conv4_w = (const float*)d_in[20];
  const float* bn4_g = (const float*)d_in[21];
  const float* bn4_b = (const float*)d_in[22];
  const float* W4 = (const float*)d_in[23];
  const float* ap4 = (const float*)d_in[24];
  const float* as4 = (const float*)d_in[25];
  const float* conv5_w = (const float*)d_in[26];
  const float* bn5_g = (const float*)d_in[27];
  const float* bn5_b = (const float*)d_in[28];
  const float* lin1_w = (const float*)d_in[29];
  const float* bn6_g = (const float*)d_in[30];
  const float* bn6_b = (const float*)d_in[31];
  const float* lin2_w = (const float*)d_in[32];
  const float* lin2_b = (const float*)d_in[33];
  const float* bn7_g = (const float*)d_in[34];
  const float* bn7_b = (const float*)d_in[35];
  const float* lin3_w = (const float*)d_in[36];
  const float* lin3_b = (const float*)d_in[37];
  (void)in_sizes; (void)n_in; (void)out_size; (void)ws_size;

  float* ws = (float*)d_ws;
  size_t off = 0;
  auto take = [&](size_t nf) {
    float* p = ws + off;
    off += (nf + 63) & ~(size_t)63;
    return p;
  };
  auto takeu = [&](size_t nu) { return (unsigned short*)take((nu + 1) / 2); };

  int* idx = (int*)take(BB * NN * KK);
  int* acode = (int*)take(BB * NN * KK);
  float* rel = take((size_t)BB * NN * KK * 2);
  unsigned short* xh = takeu((size_t)BB * NN * 2048);
  unsigned short* xl = takeu((size_t)BB * NN * 2048);
  float* pmax = take(32 * 1024);
  float* psum = take(32 * 1024);
  float* feat = take(BB * 2048);
  float* h1 = take(BB * 512);
  float* h2 = take(BB * 256);
  unsigned short* c1h = takeu(64 * 64);
  unsigned short* c1l = takeu(64 * 64);
  unsigned short* c2h = takeu(512 * 64);
  unsigned short* c2l = takeu(512 * 64);
  unsigned short* c3h = takeu(512 * 128);
  unsigned short* c3l = takeu(512 * 128);
  unsigned short* c4h = takeu(1024 * 256);
  unsigned short* c4l = takeu(1024 * 256);
  unsigned short* a1h = takeu(4 * 64 * 64);
  unsigned short* a1l = takeu(4 * 64 * 64);
  unsigned short* a2h = takeu(4 * 64 * 64);
  unsigned short* a2l = takeu(4 * 64 * 64);
  unsigned short* a3h = takeu(4 * 128 * 128);
  unsigned short* a3l = takeu(4 * 128 * 128);
  unsigned short* a4h = takeu(4 * 256 * 256);
  unsigned short* a4l = takeu(4 * 256 * 256);
  unsigned short* g5h = takeu((size_t)2048 * 1024);
  unsigned short* g5l = takeu((size_t)2048 * 1024);

  dim3 blk(256);
  dim3 blk5(512);
  k_pack<<<dim3(2, 1), blk, 0, stream>>>(conv1_w, c1h, c1l, 2, 4, 64, 0, 1, 0, 0);
  k_pack<<<dim3(16, 1), blk, 0, stream>>>(conv2_w, c2h, c2l, 16, 4, 512, 256, 1, 0, 0);
  k_pack<<<dim3(32, 1), blk, 0, stream>>>(conv3_w, c3h, c3l, 16, 8, 512, 256, 1, 0, 0);
  k_pack<<<dim3(128, 1), blk, 0, stream>>>(conv4_w, c4h, c4l, 32, 16, 1024, 512, 1, 0, 0);
  k_pack<<<dim3(2, 4), blk, 0, stream>>>(W1, a1h, a1l, 2, 4, 64, 0, 0, 64 * 64, 64 * 64);
  k_pack<<<dim3(2, 4), blk, 0, stream>>>(W2, a2h, a2l, 2, 4, 64, 0, 0, 64 * 64, 64 * 64);
  k_pack<<<dim3(8, 4), blk, 0, stream>>>(W3, a3h, a3l, 4, 8, 128, 0, 0, 128 * 128, 128 * 128);
  k_pack<<<dim3(32, 4), blk, 0, stream>>>(W4, a4h, a4l, 8, 16, 256, 0, 0, 256 * 256, 256 * 256);
  k_pack<<<dim3(1024, 1), blk, 0, stream>>>(conv5_w, g5h, g5l, 64, 64, 2048, 0, 1, 0, 0);

  k_ballquery<<<dim3(BB * NN / 4), blk, 0, stream>>>(pos, types, idx, acode, rel);

  k_layer_m<64, 64, true><<<dim3(BB * NN / 4), blk5, 0, stream>>>(
      xh, xl, 0, rel, idx, acode, c1h, c1l, a1h, a1l, bn1_g, bn1_b, ap1, as1, 0);
  k_layer_m<256, 64, false><<<dim3(BB * NN / 4), blk5, 0, stream>>>(
      xh, xl, 0, rel, idx, acode, c2h, c2l, a2h, a2l, bn2_g, bn2_b, ap2, as2, 256);
  k_layer_m<256, 128, false><<<dim3(BB * NN / 4), blk5, 0, stream>>>(
      xh, xl, 256, rel, idx, acode, c3h, c3l, a3h, a3l, bn3_g, bn3_b, ap3, as3, 512);
  k_layer_m<512, 256, false><<<dim3(BB * NN / 4), blk5, 0, stream>>>(
      xh, xl, 512, rel, idx, acode, c4h, c4l, a4h, a4l, bn4_g, bn4_b, ap4, as4, 1024);

  k_gemm5_m<<<dim3(32, 8), blk5, 0, stream>>>(xh, xl, g5h, g5l, bn5_g, bn5_b, pmax, psum);
  k_feat<<<dim3(8), blk, 0, stream>>>(pmax, psum, feat);
  k_head<false, true, true><<<dim3(BB * 512 * 64 / 256), blk, 0, stream>>>(
      feat, lin1_w, nullptr, bn6_g, bn6_b, h1, 2048, 512);
  k_head<true, true, true><<<dim3(BB * 256 * 64 / 256), blk, 0, stream>>>(
      h1, lin2_w, lin2_b, bn7_g, bn7_b, h2, 512, 256);
  k_head<true, false, false><<<dim3(1), blk, 0, stream>>>(
      h2, lin3_w, lin3_b, nullptr, nullptr, (float*)d_out, 256, 2);
}